// Round 1
// baseline (568.008 us; speedup 1.0000x reference)
//
#include <hip/hip_runtime.h>
#include <cstdint>
#include <cstddef>

// ---------------------------------------------------------------------------
// CrossAttention: out = softmax((x Wq^T)(ctx Wk^T)^T * scale) (ctx Wv^T) Wo^T + bo
// B=4, NQ=NK=2048, QDIM=CDIM=1024, H=16, DH=64, inner=1024. SCALE folded into Wq.
// All matmuls in bf16 MFMA (16x16x32), fp32 accumulation, flash-style attention.
// ---------------------------------------------------------------------------

typedef __attribute__((ext_vector_type(8))) short short8;
typedef __attribute__((ext_vector_type(4))) float f32x4;
typedef __attribute__((ext_vector_type(4))) unsigned short ushort4v;

#define GLD16(gsrc, ldst) \
  __builtin_amdgcn_global_load_lds((const __attribute__((address_space(1))) unsigned int*)(gsrc), \
                                   (__attribute__((address_space(3))) unsigned int*)(ldst), 16, 0, 0)

__device__ __forceinline__ unsigned short f32_to_bf16(float f) {
  unsigned int u = __builtin_bit_cast(unsigned int, f);
  u += 0x7FFFu + ((u >> 16) & 1u);   // RNE
  return (unsigned short)(u >> 16);
}

// ---------------- fp32 -> bf16 conversion (vectorized, optional scale) ------
__global__ __launch_bounds__(256) void cvt_bf16(const float* __restrict__ in,
                                                unsigned short* __restrict__ out,
                                                int n4, float scale) {
  int i = blockIdx.x * 256 + threadIdx.x;
  const int stride = gridDim.x * 256;
  for (; i < n4; i += stride) {
    float4 v = reinterpret_cast<const float4*>(in)[i];
    ushort4v o;
    o.x = f32_to_bf16(v.x * scale);
    o.y = f32_to_bf16(v.y * scale);
    o.z = f32_to_bf16(v.z * scale);
    o.w = f32_to_bf16(v.w * scale);
    reinterpret_cast<ushort4v*>(out)[i] = o;
  }
}

// ---------------- GEMM: C[M,N] = A[M,K] * B[N,K]^T  (bf16 in, bf16/f32 out) -
// 128x128 tile, BK=32, 256 threads (4 waves, each 64x64), global_load_lds
// staging with chunk-XOR swizzle (c ^= (row>>1)&3) to spread LDS banks.
template<bool BF16_OUT, bool BIAS>
__global__ __launch_bounds__(256) void gemm_bt(const unsigned short* __restrict__ A,
                                               const unsigned short* __restrict__ Bm,
                                               void* __restrict__ Cout,
                                               const float* __restrict__ bias,
                                               int M, int N, int K) {
  __shared__ __align__(16) unsigned short smA[128 * 32];
  __shared__ __align__(16) unsigned short smB[128 * 32];

  const int t    = threadIdx.x;
  const int lane = t & 63;
  const int wid  = t >> 6;
  const int l15  = lane & 15;
  const int l16  = lane >> 4;
  const int m0   = blockIdx.y * 128;
  const int n0   = blockIdx.x * 128;
  const int wr   = (wid >> 1) * 64;
  const int wc   = (wid & 1) * 64;

  f32x4 acc[4][4];
#pragma unroll
  for (int i = 0; i < 4; ++i)
#pragma unroll
    for (int j = 0; j < 4; ++j) acc[i][j] = (f32x4){0.f, 0.f, 0.f, 0.f};

  const char* Abase = (const char*)A + (size_t)m0 * K * 2;
  const char* Bbase = (const char*)Bm + (size_t)n0 * K * 2;

  for (int k0 = 0; k0 < K; k0 += 32) {
    // stage A,B tiles: 512 chunks of 16B each (128 rows x 4 chunks)
#pragma unroll
    for (int i = 0; i < 2; ++i) {
      int g = i * 256 + t;
      int r = g >> 2, c = g & 3;
      int cs = c ^ ((r >> 1) & 3);  // bank swizzle
      const char* srcA = Abase + (size_t)r * (K * 2) + (size_t)k0 * 2 + cs * 16;
      const char* srcB = Bbase + (size_t)r * (K * 2) + (size_t)k0 * 2 + cs * 16;
      char* dA = (char*)smA + (g & ~63) * 16;  // wave-uniform base; HW adds lane*16
      char* dB = (char*)smB + (g & ~63) * 16;
      GLD16(srcA, dA);
      GLD16(srcB, dB);
    }
    __syncthreads();

    short8 af[4], bfv[4];
#pragma unroll
    for (int mi = 0; mi < 4; ++mi) {
      int row = wr + mi * 16 + l15;
      int cs = l16 ^ ((row >> 1) & 3);
      af[mi] = *reinterpret_cast<const short8*>((const char*)smA + row * 64 + cs * 16);
    }
#pragma unroll
    for (int ni = 0; ni < 4; ++ni) {
      int row = wc + ni * 16 + l15;
      int cs = l16 ^ ((row >> 1) & 3);
      bfv[ni] = *reinterpret_cast<const short8*>((const char*)smB + row * 64 + cs * 16);
    }
#pragma unroll
    for (int mi = 0; mi < 4; ++mi)
#pragma unroll
      for (int ni = 0; ni < 4; ++ni)
        acc[mi][ni] = __builtin_amdgcn_mfma_f32_16x16x32_bf16(af[mi], bfv[ni], acc[mi][ni], 0, 0, 0);
    __syncthreads();
  }

  // epilogue: C/D layout col=lane&15, row=(lane>>4)*4+r  (m89-verified)
#pragma unroll
  for (int mi = 0; mi < 4; ++mi)
#pragma unroll
    for (int ni = 0; ni < 4; ++ni)
#pragma unroll
      for (int r = 0; r < 4; ++r) {
        int row = m0 + wr + mi * 16 + l16 * 4 + r;
        int col = n0 + wc + ni * 16 + l15;
        float v = acc[mi][ni][r];
        if (BIAS) v += bias[col];
        if (BF16_OUT)
          ((unsigned short*)Cout)[(size_t)row * N + col] = f32_to_bf16(v);
        else
          ((float*)Cout)[(size_t)row * N + col] = v;
      }
}

// ---------------- Flash attention -------------------------------------------
// Q pre-scaled. Q:(B*NQ)x1024 rows, head h at cols h*64..h*64+64.
// Kb: same layout. Vt: 1024 x 8192, row h*64+d, col b*2048+j.
// Grid (NQ/128, H, B); 256 threads = 4 waves, wave owns 32 q-rows.
// KV tiles of 64; K/V LDS tiles XOR-swizzled (c ^= row&7) -> conflict-free b128.
__global__ __launch_bounds__(256) void flash_attn(const unsigned short* __restrict__ Q,
                                                  const unsigned short* __restrict__ Kb,
                                                  const unsigned short* __restrict__ Vt,
                                                  unsigned short* __restrict__ O) {
  __shared__ __align__(16) unsigned short smK[64 * 64];
  __shared__ __align__(16) unsigned short smV[64 * 64];
  __shared__ __align__(16) unsigned short smP[4 * 32 * 72];  // per-wave 32x72 (padded)

  const int t    = threadIdx.x;
  const int lane = t & 63;
  const int wid  = t >> 6;
  const int l15  = lane & 15;
  const int l16  = lane >> 4;
  const int qt   = blockIdx.x;
  const int h    = blockIdx.y;
  const int b    = blockIdx.z;

  // Q fragments (A-operand): row = l15, k-slice = l16*8
  short8 qf[2][2];
#pragma unroll
  for (int mi = 0; mi < 2; ++mi)
#pragma unroll
    for (int kk = 0; kk < 2; ++kk) {
      size_t idx = (size_t)(b * 2048 + qt * 128 + wid * 32 + mi * 16 + l15) * 1024
                 + (size_t)h * 64 + kk * 32 + l16 * 8;
      qf[mi][kk] = *reinterpret_cast<const short8*>(&Q[idx]);
    }

  f32x4 accO[2][4];
  float m_run[2][4], l_run[2][4];
#pragma unroll
  for (int mi = 0; mi < 2; ++mi)
#pragma unroll
    for (int i = 0; i < 4; ++i) {
      accO[mi][i] = (f32x4){0.f, 0.f, 0.f, 0.f};
      m_run[mi][i] = -1.0e30f;
      l_run[mi][i] = 0.f;
    }

  const char* Kbase = (const char*)Kb + ((size_t)(b * 2048) * 1024 + h * 64) * 2;
  const char* Vbase = (const char*)Vt + ((size_t)(h * 64) * 8192 + b * 2048) * 2;
  unsigned short* smPw = smP + wid * (32 * 72);

  for (int j0 = 0; j0 < 2048; j0 += 64) {
    // stage K (64 keys x 64 d) and V^T (64 d x 64 keys), swizzled
#pragma unroll
    for (int i = 0; i < 2; ++i) {
      int g = i * 256 + t;
      int r = g >> 3, c = g & 7;
      int cs = c ^ (r & 7);
      const char* srcK = Kbase + (size_t)(j0 + r) * 2048 + cs * 16;
      const char* srcV = Vbase + (size_t)r * 16384 + (size_t)j0 * 2 + cs * 16;
      char* dK = (char*)smK + (g & ~63) * 16;
      char* dV = (char*)smV + (g & ~63) * 16;
      GLD16(srcK, dK);
      GLD16(srcV, dV);
    }
    __syncthreads();

    // S = Q K^T  (pre-scaled)
    f32x4 s[2][4];
    {
      short8 kf[4][2];
#pragma unroll
      for (int ni = 0; ni < 4; ++ni)
#pragma unroll
        for (int kk = 0; kk < 2; ++kk) {
          int row = ni * 16 + l15;
          int cs = (kk * 4 + l16) ^ (row & 7);
          kf[ni][kk] = *reinterpret_cast<const short8*>((const char*)smK + row * 128 + cs * 16);
        }
      const f32x4 z = (f32x4){0.f, 0.f, 0.f, 0.f};
#pragma unroll
      for (int mi = 0; mi < 2; ++mi)
#pragma unroll
        for (int ni = 0; ni < 4; ++ni) {
          f32x4 tmp = __builtin_amdgcn_mfma_f32_16x16x32_bf16(qf[mi][0], kf[ni][0], z, 0, 0, 0);
          s[mi][ni] = __builtin_amdgcn_mfma_f32_16x16x32_bf16(qf[mi][1], kf[ni][1], tmp, 0, 0, 0);
        }
    }

    // online softmax (fp32). Row of lane: (l16*4 + r) within 16-row frag;
    // row-reduce = across the 16 lanes sharing l16 (shfl_xor width 16).
#pragma unroll
    for (int mi = 0; mi < 2; ++mi)
#pragma unroll
      for (int r = 0; r < 4; ++r) {
        float vmax = fmaxf(fmaxf(s[mi][0][r], s[mi][1][r]), fmaxf(s[mi][2][r], s[mi][3][r]));
        vmax = fmaxf(vmax, __shfl_xor(vmax, 1, 16));
        vmax = fmaxf(vmax, __shfl_xor(vmax, 2, 16));
        vmax = fmaxf(vmax, __shfl_xor(vmax, 4, 16));
        vmax = fmaxf(vmax, __shfl_xor(vmax, 8, 16));
        float mold = m_run[mi][r];
        float mnew = fmaxf(mold, vmax);
        float alpha = __expf(mold - mnew);
        m_run[mi][r] = mnew;
        float rsum = 0.f;
#pragma unroll
        for (int ni = 0; ni < 4; ++ni) {
          float p = __expf(s[mi][ni][r] - mnew);
          s[mi][ni][r] = p;
          rsum += p;
        }
        rsum += __shfl_xor(rsum, 1, 16);
        rsum += __shfl_xor(rsum, 2, 16);
        rsum += __shfl_xor(rsum, 4, 16);
        rsum += __shfl_xor(rsum, 8, 16);
        l_run[mi][r] = l_run[mi][r] * alpha + rsum;
#pragma unroll
        for (int di = 0; di < 4; ++di) accO[mi][di][r] *= alpha;
        // P -> per-wave LDS (C-layout -> A-layout transpose via LDS)
        int prow = mi * 16 + l16 * 4 + r;
#pragma unroll
        for (int ni = 0; ni < 4; ++ni)
          smPw[prow * 72 + ni * 16 + l15] = f32_to_bf16(s[mi][ni][r]);
      }

    // PV: O += P * V   (A=P rows=q,k=j ; B=Vt n=d,k=j)
    {
      short8 pf[2][2], vf[4][2];
#pragma unroll
      for (int mi = 0; mi < 2; ++mi)
#pragma unroll
        for (int kk = 0; kk < 2; ++kk)
          pf[mi][kk] = *reinterpret_cast<const short8*>(
              (const char*)smPw + ((mi * 16 + l15) * 72 + kk * 32 + l16 * 8) * 2);
#pragma unroll
      for (int di = 0; di < 4; ++di)
#pragma unroll
        for (int kk = 0; kk < 2; ++kk) {
          int row = di * 16 + l15;
          int cs = (kk * 4 + l16) ^ (row & 7);
          vf[di][kk] = *reinterpret_cast<const short8*>((const char*)smV + row * 128 + cs * 16);
        }
#pragma unroll
      for (int mi = 0; mi < 2; ++mi)
#pragma unroll
        for (int di = 0; di < 4; ++di) {
          accO[mi][di] = __builtin_amdgcn_mfma_f32_16x16x32_bf16(pf[mi][0], vf[di][0], accO[mi][di], 0, 0, 0);
          accO[mi][di] = __builtin_amdgcn_mfma_f32_16x16x32_bf16(pf[mi][1], vf[di][1], accO[mi][di], 0, 0, 0);
        }
    }
    __syncthreads();
  }

  // epilogue: O normalized, bf16
#pragma unroll
  for (int mi = 0; mi < 2; ++mi)
#pragma unroll
    for (int r = 0; r < 4; ++r) {
      float inv = 1.f / l_run[mi][r];
      int row = b * 2048 + qt * 128 + wid * 32 + mi * 16 + l16 * 4 + r;
#pragma unroll
      for (int di = 0; di < 4; ++di) {
        int col = h * 64 + di * 16 + l15;
        O[(size_t)row * 1024 + col] = f32_to_bf16(accO[mi][di][r] * inv);
      }
    }
}

// ---------------------------------------------------------------------------
extern "C" void kernel_launch(void* const* d_in, const int* in_sizes, int n_in,
                              void* d_out, int out_size, void* d_ws, size_t ws_size,
                              hipStream_t stream) {
  (void)in_sizes; (void)n_in; (void)out_size; (void)ws_size;
  const float* x   = (const float*)d_in[0];  // 4*2048*1024
  const float* ctx = (const float*)d_in[1];  // 4*2048*1024
  const float* Wq  = (const float*)d_in[2];  // 1024*1024
  const float* Wk  = (const float*)d_in[3];
  const float* Wv  = (const float*)d_in[4];
  const float* Wo  = (const float*)d_in[5];
  const float* bo  = (const float*)d_in[6];  // 1024
  float* out = (float*)d_out;

  char* ws = (char*)d_ws;
  const size_t MB = 1024 * 1024;
  unsigned short* xb  = (unsigned short*)(ws + 0);        // 16 MB (reused as Ob after Q-proj)
  unsigned short* cb  = (unsigned short*)(ws + 16 * MB);  // 16 MB
  unsigned short* Qb  = (unsigned short*)(ws + 32 * MB);  // 16 MB
  unsigned short* Kb  = (unsigned short*)(ws + 48 * MB);  // 16 MB
  unsigned short* Vtb = (unsigned short*)(ws + 64 * MB);  // 16 MB
  unsigned short* wqb = (unsigned short*)(ws + 80 * MB);  // 2 MB each
  unsigned short* wkb = (unsigned short*)(ws + 82 * MB);
  unsigned short* wvb = (unsigned short*)(ws + 84 * MB);
  unsigned short* wob = (unsigned short*)(ws + 86 * MB);
  unsigned short* Ob  = xb;  // alias: xb dead after Q projection

  const float SCALE = 0.125f;  // DH^-0.5, folded into Wq

  // conversions
  cvt_bf16<<<2048, 256, 0, stream>>>(x,   xb,  (4*2048*1024)/4, 1.0f);
  cvt_bf16<<<2048, 256, 0, stream>>>(ctx, cb,  (4*2048*1024)/4, 1.0f);
  cvt_bf16<<<1024, 256, 0, stream>>>(Wq,  wqb, (1024*1024)/4, SCALE);
  cvt_bf16<<<1024, 256, 0, stream>>>(Wk,  wkb, (1024*1024)/4, 1.0f);
  cvt_bf16<<<1024, 256, 0, stream>>>(Wv,  wvb, (1024*1024)/4, 1.0f);
  cvt_bf16<<<1024, 256, 0, stream>>>(Wo,  wob, (1024*1024)/4, 1.0f);

  // projections: Q = xb*Wq^T (scaled), K = cb*Wk^T, Vt = Wv*cb^T (transposed out)
  gemm_bt<true, false><<<dim3(1024/128, 8192/128), 256, 0, stream>>>(xb, wqb, Qb, nullptr, 8192, 1024, 1024);
  gemm_bt<true, false><<<dim3(1024/128, 8192/128), 256, 0, stream>>>(cb, wkb, Kb, nullptr, 8192, 1024, 1024);
  gemm_bt<true, false><<<dim3(8192/128, 1024/128), 256, 0, stream>>>(wvb, cb, Vtb, nullptr, 1024, 8192, 1024);

  // flash attention -> Ob (bf16)
  flash_attn<<<dim3(2048/128, 16, 4), 256, 0, stream>>>(Qb, Kb, Vtb, Ob);

  // output projection: out = Ob*Wo^T + bo (fp32)
  gemm_bt<false, true><<<dim3(1024/128, 8192/128), 256, 0, stream>>>(Ob, wob, out, bo, 8192, 1024, 1024);
}

// Round 4
// 382.582 us; speedup vs baseline: 1.4847x; 1.4847x over previous
//
#include <hip/hip_runtime.h>
#include <cstdint>
#include <cstddef>

// ---------------------------------------------------------------------------
// CrossAttention: out = softmax((x Wq^T)(ctx Wk^T)^T * scale) (ctx Wv^T) Wo^T + bo
// B=4, NQ=NK=2048, QDIM=CDIM=1024, H=16, DH=64, inner=1024. SCALE folded into Wq.
// bf16 MFMA (16x16x32), fp32 accumulation, swapped-QK flash attention.
// ---------------------------------------------------------------------------

typedef __attribute__((ext_vector_type(8))) short short8;
typedef __attribute__((ext_vector_type(4))) float f32x4;
typedef __attribute__((ext_vector_type(4))) unsigned short ushort4v;

#define GLD16(gsrc, ldst) \
  __builtin_amdgcn_global_load_lds((const __attribute__((address_space(1))) unsigned int*)(gsrc), \
                                   (__attribute__((address_space(3))) unsigned int*)(ldst), 16, 0, 0)

__device__ __forceinline__ unsigned short f32_to_bf16(float f) {
  unsigned int u = __builtin_bit_cast(unsigned int, f);
  u += 0x7FFFu + ((u >> 16) & 1u);   // RNE
  return (unsigned short)(u >> 16);
}

__device__ __forceinline__ unsigned int pack2_bf16(float lo, float hi) {
  return (unsigned int)f32_to_bf16(lo) | ((unsigned int)f32_to_bf16(hi) << 16);
}

// ---------------- fp32 -> bf16 conversion (vectorized, optional scale) ------
__global__ __launch_bounds__(256) void cvt_bf16(const float* __restrict__ in,
                                                unsigned short* __restrict__ out,
                                                int n4, float scale) {
  int i = blockIdx.x * 256 + threadIdx.x;
  const int stride = gridDim.x * 256;
  for (; i < n4; i += stride) {
    float4 v = reinterpret_cast<const float4*>(in)[i];
    ushort4v o;
    o.x = f32_to_bf16(v.x * scale);
    o.y = f32_to_bf16(v.y * scale);
    o.z = f32_to_bf16(v.z * scale);
    o.w = f32_to_bf16(v.w * scale);
    reinterpret_cast<ushort4v*>(out)[i] = o;
  }
}

// ---------------- GEMM: C[M,N] = A[M,K] * B[N,K]^T  (unchanged, passing) ----
template<bool BF16_OUT, bool BIAS>
__global__ __launch_bounds__(256) void gemm_bt(const unsigned short* __restrict__ A,
                                               const unsigned short* __restrict__ Bm,
                                               void* __restrict__ Cout,
                                               const float* __restrict__ bias,
                                               int M, int N, int K) {
  __shared__ __align__(16) unsigned short smA[128 * 32];
  __shared__ __align__(16) unsigned short smB[128 * 32];

  const int t    = threadIdx.x;
  const int lane = t & 63;
  const int wid  = t >> 6;
  const int l15  = lane & 15;
  const int l16  = lane >> 4;
  const int m0   = blockIdx.y * 128;
  const int n0   = blockIdx.x * 128;
  const int wr   = (wid >> 1) * 64;
  const int wc   = (wid & 1) * 64;

  f32x4 acc[4][4];
#pragma unroll
  for (int i = 0; i < 4; ++i)
#pragma unroll
    for (int j = 0; j < 4; ++j) acc[i][j] = (f32x4){0.f, 0.f, 0.f, 0.f};

  const char* Abase = (const char*)A + (size_t)m0 * K * 2;
  const char* Bbase = (const char*)Bm + (size_t)n0 * K * 2;

  for (int k0 = 0; k0 < K; k0 += 32) {
#pragma unroll
    for (int i = 0; i < 2; ++i) {
      int g = i * 256 + t;
      int r = g >> 2, c = g & 3;
      int cs = c ^ ((r >> 1) & 3);
      const char* srcA = Abase + (size_t)r * (K * 2) + (size_t)k0 * 2 + cs * 16;
      const char* srcB = Bbase + (size_t)r * (K * 2) + (size_t)k0 * 2 + cs * 16;
      char* dA = (char*)smA + (g & ~63) * 16;
      char* dB = (char*)smB + (g & ~63) * 16;
      GLD16(srcA, dA);
      GLD16(srcB, dB);
    }
    __syncthreads();

    short8 af[4], bfv[4];
#pragma unroll
    for (int mi = 0; mi < 4; ++mi) {
      int row = wr + mi * 16 + l15;
      int cs = l16 ^ ((row >> 1) & 3);
      af[mi] = *reinterpret_cast<const short8*>((const char*)smA + row * 64 + cs * 16);
    }
#pragma unroll
    for (int ni = 0; ni < 4; ++ni) {
      int row = wc + ni * 16 + l15;
      int cs = l16 ^ ((row >> 1) & 3);
      bfv[ni] = *reinterpret_cast<const short8*>((const char*)smB + row * 64 + cs * 16);
    }
#pragma unroll
    for (int mi = 0; mi < 4; ++mi)
#pragma unroll
      for (int ni = 0; ni < 4; ++ni)
        acc[mi][ni] = __builtin_amdgcn_mfma_f32_16x16x32_bf16(af[mi], bfv[ni], acc[mi][ni], 0, 0, 0);
    __syncthreads();
  }

#pragma unroll
  for (int mi = 0; mi < 4; ++mi)
#pragma unroll
    for (int ni = 0; ni < 4; ++ni)
#pragma unroll
      for (int r = 0; r < 4; ++r) {
        int row = m0 + wr + mi * 16 + l16 * 4 + r;
        int col = n0 + wc + ni * 16 + l15;
        float v = acc[mi][ni][r];
        if (BIAS) v += bias[col];
        if (BF16_OUT)
          ((unsigned short*)Cout)[(size_t)row * N + col] = f32_to_bf16(v);
        else
          ((float*)Cout)[(size_t)row * N + col] = v;
      }
}

// ---------------- Flash attention v2: swapped QK^T --------------------------
// S^T = mfma(A=K, B=Q): C col=l15=q, row=l16*4+r=k (within 16-k chunk kc).
// Softmax: 15 in-lane fmax + 2 shfl_xor. P transposed to A-layout via
// wave-private LDS [32][36 words] (8 ds_write_b64 + 4 ds_read_b128, no barrier).
// K/V double-buffered via global_load_lds + counted vmcnt(4) + raw s_barrier.
__global__ __launch_bounds__(256, 3) void flash_attn(const unsigned short* __restrict__ Q,
                                                     const unsigned short* __restrict__ Kb,
                                                     const unsigned short* __restrict__ Vt,
                                                     unsigned short* __restrict__ O) {
  __shared__ __align__(16) unsigned short smK[2][64 * 64];
  __shared__ __align__(16) unsigned short smV[2][64 * 64];
  __shared__ __align__(16) unsigned int   smP[4][32 * 36];  // per-wave P, padded

  const int t    = threadIdx.x;
  const int lane = t & 63;
  const int wid  = t >> 6;
  const int l15  = lane & 15;
  const int l16  = lane >> 4;
  const int qt   = blockIdx.x;
  const int h    = blockIdx.y;
  const int b    = blockIdx.z;

  const char* Kbase = (const char*)Kb + ((size_t)(b * 2048) * 1024 + h * 64) * 2;
  const char* Vbase = (const char*)Vt + ((size_t)(h * 64) * 8192 + b * 2048) * 2;
  unsigned int* smPw = &smP[wid][0];

  // Q as B-operand: col(q)=l15, d-elems = kk*32 + l16*8 + j
  short8 qf[2][2];
#pragma unroll
  for (int qg = 0; qg < 2; ++qg)
#pragma unroll
    for (int kk = 0; kk < 2; ++kk) {
      size_t idx = (size_t)(b * 2048 + qt * 128 + wid * 32 + qg * 16 + l15) * 1024
                 + (size_t)h * 64 + kk * 32 + l16 * 8;
      qf[qg][kk] = *reinterpret_cast<const short8*>(&Q[idx]);
    }
  // drain Q loads so the only in-flight vmem ops are staging GLDs
  asm volatile("s_waitcnt vmcnt(0)" ::: "memory");
  __builtin_amdgcn_sched_barrier(0);

  auto stage = [&](int buf, int j0) {
#pragma unroll
    for (int i = 0; i < 2; ++i) {
      int g = i * 256 + t;
      int r = g >> 3, c = g & 7;
      int cs = c ^ (r & 7);
      const char* srcK = Kbase + (size_t)(j0 + r) * 2048 + cs * 16;
      const char* srcV = Vbase + (size_t)r * 16384 + (size_t)j0 * 2 + cs * 16;
      GLD16(srcK, (char*)&smK[buf][0] + (g & ~63) * 16);
      GLD16(srcV, (char*)&smV[buf][0] + (g & ~63) * 16);
    }
  };

  f32x4 accO[2][4];
  float m_run[2], l_run[2];
#pragma unroll
  for (int qg = 0; qg < 2; ++qg) {
    m_run[qg] = -1.0e30f;
    l_run[qg] = 0.f;
#pragma unroll
    for (int di = 0; di < 4; ++di) accO[qg][di] = (f32x4){0.f, 0.f, 0.f, 0.f};
  }

  stage(0, 0);

  for (int jt = 0; jt < 32; ++jt) {
    const int buf = jt & 1;
    if (jt < 31) {
      stage(buf ^ 1, (jt + 1) * 64);
      asm volatile("s_waitcnt vmcnt(4)" ::: "memory");  // current tile's 4 GLDs done
    } else {
      asm volatile("s_waitcnt vmcnt(0)" ::: "memory");
    }
    __builtin_amdgcn_sched_barrier(0);
    __builtin_amdgcn_s_barrier();

    // ---- QK^T (swapped): s[qg][kc], col=q, row=k ----
    short8 kf[4][2];
#pragma unroll
    for (int kc = 0; kc < 4; ++kc)
#pragma unroll
      for (int kk = 0; kk < 2; ++kk) {
        int row = kc * 16 + l15;
        int cs = (kk * 4 + l16) ^ (row & 7);
        kf[kc][kk] = *reinterpret_cast<const short8*>((const char*)&smK[buf][0] + row * 128 + cs * 16);
      }
    f32x4 s[2][4];
    const f32x4 z = (f32x4){0.f, 0.f, 0.f, 0.f};
    __builtin_amdgcn_s_setprio(1);
#pragma unroll
    for (int qg = 0; qg < 2; ++qg)
#pragma unroll
      for (int kc = 0; kc < 4; ++kc) {
        f32x4 tmp = __builtin_amdgcn_mfma_f32_16x16x32_bf16(kf[kc][0], qf[qg][0], z, 0, 0, 0);
        s[qg][kc] = __builtin_amdgcn_mfma_f32_16x16x32_bf16(kf[kc][1], qf[qg][1], tmp, 0, 0, 0);
      }
    __builtin_amdgcn_s_setprio(0);

    // ---- V fragments (issue early: DS runs under softmax VALU) ----
    short8 vf[4][2];
#pragma unroll
    for (int di = 0; di < 4; ++di)
#pragma unroll
      for (int kk = 0; kk < 2; ++kk) {
        int row = di * 16 + l15;
        int cs = (kk * 4 + l16) ^ (row & 7);
        vf[di][kk] = *reinterpret_cast<const short8*>((const char*)&smV[buf][0] + row * 128 + cs * 16);
      }

    // ---- online softmax (lane owns q = qg*16+l15; k in regs) ----
#pragma unroll
    for (int qg = 0; qg < 2; ++qg) {
      float vmax = s[qg][0][0];
#pragma unroll
      for (int kc = 0; kc < 4; ++kc)
#pragma unroll
        for (int r = 0; r < 4; ++r) vmax = fmaxf(vmax, s[qg][kc][r]);
      vmax = fmaxf(vmax, __shfl_xor(vmax, 16));
      vmax = fmaxf(vmax, __shfl_xor(vmax, 32));

      if (__any(vmax > m_run[qg] + 8.0f)) {   // T13 defer-max
        float mnew = fmaxf(m_run[qg], vmax);
        float alpha = __expf(m_run[qg] - mnew);
        m_run[qg] = mnew;
        l_run[qg] *= alpha;
        int av = __builtin_bit_cast(int, alpha);
#pragma unroll
        for (int r = 0; r < 4; ++r) {
          float at = __builtin_bit_cast(float, __builtin_amdgcn_ds_bpermute((l16 * 4 + r) * 4, av));
#pragma unroll
          for (int di = 0; di < 4; ++di) accO[qg][di][r] *= at;
        }
      }

      float rsum = 0.f;
#pragma unroll
      for (int kc = 0; kc < 4; ++kc)
#pragma unroll
        for (int r = 0; r < 4; ++r) {
          float p = __expf(s[qg][kc][r] - m_run[qg]);
          s[qg][kc][r] = p;
          rsum += p;
        }
      rsum += __shfl_xor(rsum, 16);
      rsum += __shfl_xor(rsum, 32);
      l_run[qg] += rsum;

      // pack pairs (k, k+1) and write to wave-private P-LDS
#pragma unroll
      for (int kc = 0; kc < 4; ++kc) {
        unsigned int w0 = pack2_bf16(s[qg][kc][0], s[qg][kc][1]);
        unsigned int w1 = pack2_bf16(s[qg][kc][2], s[qg][kc][3]);
        int word = (qg * 16 + l15) * 36 + kc * 8 + l16 * 2;
        *reinterpret_cast<uint2*>(&smPw[word]) = uint2{w0, w1};
      }
    }

    // same-wave DS ordering: ensure P writes landed before A-frag reads
    asm volatile("s_waitcnt lgkmcnt(0)" ::: "memory");
    __builtin_amdgcn_sched_barrier(0);

    short8 pf[2][2];
#pragma unroll
    for (int qg = 0; qg < 2; ++qg)
#pragma unroll
      for (int kk = 0; kk < 2; ++kk) {
        int word = (qg * 16 + l15) * 36 + kk * 16 + l16 * 4;
        pf[qg][kk] = *reinterpret_cast<const short8*>(&smPw[word]);
      }

    __builtin_amdgcn_s_setprio(1);
#pragma unroll
    for (int qg = 0; qg < 2; ++qg)
#pragma unroll
      for (int di = 0; di < 4; ++di) {
        accO[qg][di] = __builtin_amdgcn_mfma_f32_16x16x32_bf16(pf[qg][0], vf[di][0], accO[qg][di], 0, 0, 0);
        accO[qg][di] = __builtin_amdgcn_mfma_f32_16x16x32_bf16(pf[qg][1], vf[di][1], accO[qg][di], 0, 0, 0);
      }
    __builtin_amdgcn_s_setprio(0);

    __builtin_amdgcn_s_barrier();  // protect K/V buf before next restage
  }

  // ---- epilogue: normalize (transpose 1/l to accO rows) and store ----
#pragma unroll
  for (int qg = 0; qg < 2; ++qg) {
    float inv = 1.f / l_run[qg];
    int iv = __builtin_bit_cast(int, inv);
#pragma unroll
    for (int r = 0; r < 4; ++r) {
      float it = __builtin_bit_cast(float, __builtin_amdgcn_ds_bpermute((l16 * 4 + r) * 4, iv));
      int row = b * 2048 + qt * 128 + wid * 32 + qg * 16 + l16 * 4 + r;
#pragma unroll
      for (int di = 0; di < 4; ++di) {
        int col = h * 64 + di * 16 + l15;
        O[(size_t)row * 1024 + col] = f32_to_bf16(accO[qg][di][r] * it);
      }
    }
  }
}

// ---------------------------------------------------------------------------
extern "C" void kernel_launch(void* const* d_in, const int* in_sizes, int n_in,
                              void* d_out, int out_size, void* d_ws, size_t ws_size,
                              hipStream_t stream) {
  (void)in_sizes; (void)n_in; (void)out_size; (void)ws_size;
  const float* x   = (const float*)d_in[0];
  const float* ctx = (const float*)d_in[1];
  const float* Wq  = (const float*)d_in[2];
  const float* Wk  = (const float*)d_in[3];
  const float* Wv  = (const float*)d_in[4];
  const float* Wo  = (const float*)d_in[5];
  const float* bo  = (const float*)d_in[6];
  float* out = (float*)d_out;

  char* ws = (char*)d_ws;
  const size_t MB = 1024 * 1024;
  unsigned short* xb  = (unsigned short*)(ws + 0);
  unsigned short* cb  = (unsigned short*)(ws + 16 * MB);
  unsigned short* Qb  = (unsigned short*)(ws + 32 * MB);
  unsigned short* Kb  = (unsigned short*)(ws + 48 * MB);
  unsigned short* Vtb = (unsigned short*)(ws + 64 * MB);
  unsigned short* wqb = (unsigned short*)(ws + 80 * MB);
  unsigned short* wkb = (unsigned short*)(ws + 82 * MB);
  unsigned short* wvb = (unsigned short*)(ws + 84 * MB);
  unsigned short* wob = (unsigned short*)(ws + 86 * MB);
  unsigned short* Ob  = xb;  // alias: xb dead after Q projection

  const float SCALE = 0.125f;

  cvt_bf16<<<2048, 256, 0, stream>>>(x,   xb,  (4*2048*1024)/4, 1.0f);
  cvt_bf16<<<2048, 256, 0, stream>>>(ctx, cb,  (4*2048*1024)/4, 1.0f);
  cvt_bf16<<<1024, 256, 0, stream>>>(Wq,  wqb, (1024*1024)/4, SCALE);
  cvt_bf16<<<1024, 256, 0, stream>>>(Wk,  wkb, (1024*1024)/4, 1.0f);
  cvt_bf16<<<1024, 256, 0, stream>>>(Wv,  wvb, (1024*1024)/4, 1.0f);
  cvt_bf16<<<1024, 256, 0, stream>>>(Wo,  wob, (1024*1024)/4, 1.0f);

  gemm_bt<true, false><<<dim3(1024/128, 8192/128), 256, 0, stream>>>(xb, wqb, Qb, nullptr, 8192, 1024, 1024);
  gemm_bt<true, false><<<dim3(1024/128, 8192/128), 256, 0, stream>>>(cb, wkb, Kb, nullptr, 8192, 1024, 1024);
  gemm_bt<true, false><<<dim3(8192/128, 1024/128), 256, 0, stream>>>(wvb, cb, Vtb, nullptr, 1024, 8192, 1024);

  flash_attn<<<dim3(2048/128, 16, 4), 256, 0, stream>>>(Qb, Kb, Vtb, Ob);

  gemm_bt<false, true><<<dim3(1024/128, 8192/128), 256, 0, stream>>>(Ob, wob, out, bo, 8192, 1024, 1024);
}

// Round 6
// 355.166 us; speedup vs baseline: 1.5993x; 1.0772x over previous
//
#include <hip/hip_runtime.h>
#include <cstdint>
#include <cstddef>

// ---------------------------------------------------------------------------
// CrossAttention: out = softmax((x Wq^T)(ctx Wk^T)^T * scale) (ctx Wv^T) Wo^T + bo
// B=4, NQ=NK=2048, QDIM=CDIM=1024, H=16, DH=64, inner=1024.
// SCALE*log2(e) folded into Wq; softmax in exp2 domain.
// bf16 MFMA (16x16x32), fp32 accumulation, swapped-QK flash attention.
// All staged kernels use the single-barrier 2-phase pipeline (T3-minimal):
//   stage(next) -> compute(cur) -> vmcnt(0) -> s_barrier.
// ---------------------------------------------------------------------------

typedef __attribute__((ext_vector_type(8))) short short8;
typedef __attribute__((ext_vector_type(4))) float f32x4;
typedef __attribute__((ext_vector_type(4))) unsigned short ushort4v;

#define GLD16(gsrc, ldst) \
  __builtin_amdgcn_global_load_lds((const __attribute__((address_space(1))) unsigned int*)(gsrc), \
                                   (__attribute__((address_space(3))) unsigned int*)(ldst), 16, 0, 0)

__device__ __forceinline__ unsigned short f32_to_bf16(float f) {
  unsigned int u = __builtin_bit_cast(unsigned int, f);
  u += 0x7FFFu + ((u >> 16) & 1u);   // RNE
  return (unsigned short)(u >> 16);
}

// T12: packed f32x2 -> bf16x2, single VALU op (no builtin on gfx950; asm per guide)
__device__ __forceinline__ unsigned int cvtpk_bf16(float lo, float hi) {
  unsigned int r;
  asm("v_cvt_pk_bf16_f32 %0, %1, %2" : "=v"(r) : "v"(lo), "v"(hi));
  return r;
}

__device__ __forceinline__ float exp2_fast(float x) {
#if __has_builtin(__builtin_amdgcn_exp2f)
  return __builtin_amdgcn_exp2f(x);
#else
  return exp2f(x);
#endif
}

// ---------------- fp32 -> bf16 conversion (vectorized, optional scale) ------
__global__ __launch_bounds__(256) void cvt_bf16(const float* __restrict__ in,
                                                unsigned short* __restrict__ out,
                                                int n4, float scale) {
  int i = blockIdx.x * 256 + threadIdx.x;
  const int stride = gridDim.x * 256;
  for (; i < n4; i += stride) {
    float4 v = reinterpret_cast<const float4*>(in)[i];
    ushort4v o;
    o.x = f32_to_bf16(v.x * scale);
    o.y = f32_to_bf16(v.y * scale);
    o.z = f32_to_bf16(v.z * scale);
    o.w = f32_to_bf16(v.w * scale);
    reinterpret_cast<ushort4v*>(out)[i] = o;
  }
}

// 4 weight matrices (1024x1024 each) in one launch; scale applied to w0 only.
__global__ __launch_bounds__(256) void cvt_w4(const float* __restrict__ a, const float* __restrict__ b,
                                              const float* __restrict__ c, const float* __restrict__ d,
                                              unsigned short* __restrict__ oa, unsigned short* __restrict__ ob,
                                              unsigned short* __restrict__ oc, unsigned short* __restrict__ od,
                                              float scale_a) {
  int seg = blockIdx.x >> 8;          // 0..3
  int blk = blockIdx.x & 255;
  const float* in = seg == 0 ? a : seg == 1 ? b : seg == 2 ? c : d;
  unsigned short* out = seg == 0 ? oa : seg == 1 ? ob : seg == 2 ? oc : od;
  float sc = seg == 0 ? scale_a : 1.0f;
  int i = blk * 256 + threadIdx.x;
#pragma unroll
  for (int k = 0; k < 4; ++k, i += 65536) {
    float4 v = reinterpret_cast<const float4*>(in)[i];
    ushort4v o;
    o.x = f32_to_bf16(v.x * sc);
    o.y = f32_to_bf16(v.y * sc);
    o.z = f32_to_bf16(v.z * sc);
    o.w = f32_to_bf16(v.w * sc);
    reinterpret_cast<ushort4v*>(out)[i] = o;
  }
}

// ---------------- GEMM: C[M,N] = A[M,K] * B[N,K]^T  (bf16 in, bf16/f32 out) -
// 128x128 tile, BK=32, double-buffered LDS, single-barrier 2-phase pipeline.
template<bool BF16_OUT, bool BIAS>
__global__ __launch_bounds__(256) void gemm_bt(const unsigned short* __restrict__ A,
                                               const unsigned short* __restrict__ Bm,
                                               void* __restrict__ Cout,
                                               const float* __restrict__ bias,
                                               int M, int N, int K) {
  __shared__ __align__(16) unsigned short smA[2][128 * 32];
  __shared__ __align__(16) unsigned short smB[2][128 * 32];

  const int t    = threadIdx.x;
  const int lane = t & 63;
  const int wid  = t >> 6;
  const int l15  = lane & 15;
  const int l16  = lane >> 4;
  const int m0   = blockIdx.y * 128;
  const int n0   = blockIdx.x * 128;
  const int wr   = (wid >> 1) * 64;
  const int wc   = (wid & 1) * 64;

  f32x4 acc[4][4];
#pragma unroll
  for (int i = 0; i < 4; ++i)
#pragma unroll
    for (int j = 0; j < 4; ++j) acc[i][j] = (f32x4){0.f, 0.f, 0.f, 0.f};

  const char* Abase = (const char*)A + (size_t)m0 * K * 2;
  const char* Bbase = (const char*)Bm + (size_t)n0 * K * 2;

  auto stageG = [&](int bufi, int k0) {
#pragma unroll
    for (int i = 0; i < 2; ++i) {
      int g = i * 256 + t;
      int r = g >> 2, c = g & 3;
      int cs = c ^ ((r >> 1) & 3);  // bank swizzle
      GLD16(Abase + (size_t)r * (K * 2) + (size_t)k0 * 2 + cs * 16,
            (char*)&smA[bufi][0] + (g & ~63) * 16);
      GLD16(Bbase + (size_t)r * (K * 2) + (size_t)k0 * 2 + cs * 16,
            (char*)&smB[bufi][0] + (g & ~63) * 16);
    }
  };

  const int nk = K >> 5;
  stageG(0, 0);
  asm volatile("s_waitcnt vmcnt(0)" ::: "memory");
  __builtin_amdgcn_s_barrier();

  for (int t0 = 0; t0 < nk; ++t0) {
    const int bufi = t0 & 1;
    if (t0 + 1 < nk) stageG(bufi ^ 1, (t0 + 1) * 32);

    short8 af[4], bfv[4];
#pragma unroll
    for (int mi = 0; mi < 4; ++mi) {
      int row = wr + mi * 16 + l15;
      int cs = l16 ^ ((row >> 1) & 3);
      af[mi] = *reinterpret_cast<const short8*>((const char*)&smA[bufi][0] + row * 64 + cs * 16);
    }
#pragma unroll
    for (int ni = 0; ni < 4; ++ni) {
      int row = wc + ni * 16 + l15;
      int cs = l16 ^ ((row >> 1) & 3);
      bfv[ni] = *reinterpret_cast<const short8*>((const char*)&smB[bufi][0] + row * 64 + cs * 16);
    }
    __builtin_amdgcn_s_setprio(1);
#pragma unroll
    for (int mi = 0; mi < 4; ++mi)
#pragma unroll
      for (int ni = 0; ni < 4; ++ni)
        acc[mi][ni] = __builtin_amdgcn_mfma_f32_16x16x32_bf16(af[mi], bfv[ni], acc[mi][ni], 0, 0, 0);
    __builtin_amdgcn_s_setprio(0);

    asm volatile("s_waitcnt vmcnt(0)" ::: "memory");  // next-tile loads landed
    __builtin_amdgcn_s_barrier();
  }

  // epilogue: C/D layout col=lane&15, row=(lane>>4)*4+r
#pragma unroll
  for (int mi = 0; mi < 4; ++mi)
#pragma unroll
    for (int ni = 0; ni < 4; ++ni)
#pragma unroll
      for (int r = 0; r < 4; ++r) {
        int row = m0 + wr + mi * 16 + l16 * 4 + r;
        int col = n0 + wc + ni * 16 + l15;
        float v = acc[mi][ni][r];
        if (BIAS) v += bias[col];
        if (BF16_OUT)
          ((unsigned short*)Cout)[(size_t)row * N + col] = f32_to_bf16(v);
        else
          ((float*)Cout)[(size_t)row * N + col] = v;
      }
}

// ---------------- Flash attention v3 ----------------------------------------
// Swapped QK^T (S^T = mfma(A=K, B=Q)): C col=l15=q, row=l16*4+r=k.
// exp2-domain softmax (log2e folded into Wq). P pack via v_cvt_pk_bf16_f32.
// Single-barrier 2-phase pipeline: stage(next) overlaps full tile compute.
__global__ __launch_bounds__(256, 3) void flash_attn(const unsigned short* __restrict__ Q,
                                                     const unsigned short* __restrict__ Kb,
                                                     const unsigned short* __restrict__ Vt,
                                                     unsigned short* __restrict__ O) {
  __shared__ __align__(16) unsigned short smK[2][64 * 64];
  __shared__ __align__(16) unsigned short smV[2][64 * 64];
  __shared__ __align__(16) unsigned int   smP[4][32 * 36];  // per-wave P, padded

  const int t    = threadIdx.x;
  const int lane = t & 63;
  const int wid  = t >> 6;
  const int l15  = lane & 15;
  const int l16  = lane >> 4;
  const int qt   = blockIdx.x;
  const int h    = blockIdx.y;
  const int b    = blockIdx.z;

  const char* Kbase = (const char*)Kb + ((size_t)(b * 2048) * 1024 + h * 64) * 2;
  const char* Vbase = (const char*)Vt + ((size_t)(h * 64) * 8192 + b * 2048) * 2;
  unsigned int* smPw = &smP[wid][0];

  auto stage = [&](int buf, int j0) {
#pragma unroll
    for (int i = 0; i < 2; ++i) {
      int g = i * 256 + t;
      int r = g >> 3, c = g & 7;
      int cs = c ^ (r & 7);
      const char* srcK = Kbase + (size_t)(j0 + r) * 2048 + cs * 16;
      const char* srcV = Vbase + (size_t)r * 16384 + (size_t)j0 * 2 + cs * 16;
      GLD16(srcK, (char*)&smK[buf][0] + (g & ~63) * 16);
      GLD16(srcV, (char*)&smV[buf][0] + (g & ~63) * 16);
    }
  };

  stage(0, 0);

  // Q as B-operand: col(q)=l15, d-elems = kk*32 + l16*8 + j
  short8 qf[2][2];
#pragma unroll
  for (int qg = 0; qg < 2; ++qg)
#pragma unroll
    for (int kk = 0; kk < 2; ++kk) {
      size_t idx = (size_t)(b * 2048 + qt * 128 + wid * 32 + qg * 16 + l15) * 1024
                 + (size_t)h * 64 + kk * 32 + l16 * 8;
      qf[qg][kk] = *reinterpret_cast<const short8*>(&Q[idx]);
    }

  f32x4 accO[2][4];
  float m_run[2], l_run[2];
#pragma unroll
  for (int qg = 0; qg < 2; ++qg) {
    m_run[qg] = -1.0e30f;
    l_run[qg] = 0.f;
#pragma unroll
    for (int di = 0; di < 4; ++di) accO[qg][di] = (f32x4){0.f, 0.f, 0.f, 0.f};
  }

  asm volatile("s_waitcnt vmcnt(0)" ::: "memory");
  __builtin_amdgcn_s_barrier();

  for (int jt = 0; jt < 32; ++jt) {
    const int buf = jt & 1;
    if (jt < 31) stage(buf ^ 1, (jt + 1) * 64);  // overlaps entire tile compute

    // ---- QK^T (swapped): s[qg][kc], col=q, row=k ----
    short8 kf[4][2];
#pragma unroll
    for (int kc = 0; kc < 4; ++kc)
#pragma unroll
      for (int kk = 0; kk < 2; ++kk) {
        int row = kc * 16 + l15;
        int cs = (kk * 4 + l16) ^ (row & 7);
        kf[kc][kk] = *reinterpret_cast<const short8*>((const char*)&smK[buf][0] + row * 128 + cs * 16);
      }
    f32x4 s[2][4];
    const f32x4 z = (f32x4){0.f, 0.f, 0.f, 0.f};
    __builtin_amdgcn_s_setprio(1);
#pragma unroll
    for (int qg = 0; qg < 2; ++qg)
#pragma unroll
      for (int kc = 0; kc < 4; ++kc) {
        f32x4 tmp = __builtin_amdgcn_mfma_f32_16x16x32_bf16(kf[kc][0], qf[qg][0], z, 0, 0, 0);
        s[qg][kc] = __builtin_amdgcn_mfma_f32_16x16x32_bf16(kf[kc][1], qf[qg][1], tmp, 0, 0, 0);
      }
    __builtin_amdgcn_s_setprio(0);

    // ---- V fragments (DS issues under softmax VALU) ----
    short8 vf[4][2];
#pragma unroll
    for (int di = 0; di < 4; ++di)
#pragma unroll
      for (int kk = 0; kk < 2; ++kk) {
        int row = di * 16 + l15;
        int cs = (kk * 4 + l16) ^ (row & 7);
        vf[di][kk] = *reinterpret_cast<const short8*>((const char*)&smV[buf][0] + row * 128 + cs * 16);
      }

    // ---- online softmax, exp2 domain (lane owns q = qg*16+l15) ----
#pragma unroll
    for (int qg = 0; qg < 2; ++qg) {
      float vmax = s[qg][0][0];
#pragma unroll
      for (int kc = 0; kc < 4; ++kc)
#pragma unroll
        for (int r = 0; r < 4; ++r) vmax = fmaxf(vmax, s[qg][kc][r]);
      vmax = fmaxf(vmax, __shfl_xor(vmax, 16));
      vmax = fmaxf(vmax, __shfl_xor(vmax, 32));

      if (__any(vmax > m_run[qg] + 11.5f)) {   // T13 defer-max (2^11.5 ~ e^8)
        float mnew = fmaxf(m_run[qg], vmax);
        float alpha = exp2_fast(m_run[qg] - mnew);
        m_run[qg] = mnew;
        l_run[qg] *= alpha;
        int av = __builtin_bit_cast(int, alpha);
#pragma unroll
        for (int r = 0; r < 4; ++r) {
          float at = __builtin_bit_cast(float, __builtin_amdgcn_ds_bpermute((l16 * 4 + r) * 4, av));
#pragma unroll
          for (int di = 0; di < 4; ++di) accO[qg][di][r] *= at;
        }
      }

      float rsum = 0.f;
#pragma unroll
      for (int kc = 0; kc < 4; ++kc)
#pragma unroll
        for (int r = 0; r < 4; ++r) {
          float p = exp2_fast(s[qg][kc][r] - m_run[qg]);
          s[qg][kc][r] = p;
          rsum += p;
        }
      rsum += __shfl_xor(rsum, 16);
      rsum += __shfl_xor(rsum, 32);
      l_run[qg] += rsum;

      // pack pairs (k, k+1) via cvt_pk and write to wave-private P-LDS
#pragma unroll
      for (int kc = 0; kc < 4; ++kc) {
        unsigned int w0 = cvtpk_bf16(s[qg][kc][0], s[qg][kc][1]);
        unsigned int w1 = cvtpk_bf16(s[qg][kc][2], s[qg][kc][3]);
        int word = (qg * 16 + l15) * 36 + kc * 8 + l16 * 2;
        *reinterpret_cast<uint2*>(&smPw[word]) = uint2{w0, w1};
      }
    }

    // same-wave DS ordering: P writes landed before A-frag reads
    asm volatile("s_waitcnt lgkmcnt(0)" ::: "memory");
    __builtin_amdgcn_sched_barrier(0);

    short8 pf[2][2];
#pragma unroll
    for (int qg = 0; qg < 2; ++qg)
#pragma unroll
      for (int kk = 0; kk < 2; ++kk) {
        int word = (qg * 16 + l15) * 36 + kk * 16 + l16 * 4;
        pf[qg][kk] = *reinterpret_cast<const short8*>(&smPw[word]);
      }

    __builtin_amdgcn_s_setprio(1);
#pragma unroll
    for (int qg = 0; qg < 2; ++qg)
#pragma unroll
      for (int di = 0; di < 4; ++di) {
        accO[qg][di] = __builtin_amdgcn_mfma_f32_16x16x32_bf16(pf[qg][0], vf[di][0], accO[qg][di], 0, 0, 0);
        accO[qg][di] = __builtin_amdgcn_mfma_f32_16x16x32_bf16(pf[qg][1], vf[di][1], accO[qg][di], 0, 0, 0);
      }
    __builtin_amdgcn_s_setprio(0);

    asm volatile("s_waitcnt vmcnt(0)" ::: "memory");  // next-tile stage landed
    __builtin_amdgcn_s_barrier();
  }

  // ---- epilogue: normalize (transpose 1/l to accO rows) and store ----
#pragma unroll
  for (int qg = 0; qg < 2; ++qg) {
    float inv = 1.f / l_run[qg];
    int iv = __builtin_bit_cast(int, inv);
#pragma unroll
    for (int r = 0; r < 4; ++r) {
      float it = __builtin_bit_cast(float, __builtin_amdgcn_ds_bpermute((l16 * 4 + r) * 4, iv));
      int row = b * 2048 + qt * 128 + wid * 32 + qg * 16 + l16 * 4 + r;
#pragma unroll
      for (int di = 0; di < 4; ++di) {
        int col = h * 64 + di * 16 + l15;
        O[(size_t)row * 1024 + col] = f32_to_bf16(accO[qg][di][r] * it);
      }
    }
  }
}

// ---------------------------------------------------------------------------
extern "C" void kernel_launch(void* const* d_in, const int* in_sizes, int n_in,
                              void* d_out, int out_size, void* d_ws, size_t ws_size,
                              hipStream_t stream) {
  (void)in_sizes; (void)n_in; (void)out_size; (void)ws_size;
  const float* x   = (const float*)d_in[0];
  const float* ctx = (const float*)d_in[1];
  const float* Wq  = (const float*)d_in[2];
  const float* Wk  = (const float*)d_in[3];
  const float* Wv  = (const float*)d_in[4];
  const float* Wo  = (const float*)d_in[5];
  const float* bo  = (const float*)d_in[6];
  float* out = (float*)d_out;

  char* ws = (char*)d_ws;
  const size_t MB = 1024 * 1024;
  unsigned short* xb  = (unsigned short*)(ws + 0);
  unsigned short* cb  = (unsigned short*)(ws + 16 * MB);
  unsigned short* Qb  = (unsigned short*)(ws + 32 * MB);
  unsigned short* Kb  = (unsigned short*)(ws + 48 * MB);
  unsigned short* Vtb = (unsigned short*)(ws + 64 * MB);
  unsigned short* wqb = (unsigned short*)(ws + 80 * MB);
  unsigned short* wkb = (unsigned short*)(ws + 82 * MB);
  unsigned short* wvb = (unsigned short*)(ws + 84 * MB);
  unsigned short* wob = (unsigned short*)(ws + 86 * MB);
  unsigned short* Ob  = xb;  // alias: xb dead after Q projection

  const float SCALE_LOG2E = 0.125f * 1.4426950408889634f;  // DH^-0.5 * log2(e)

  cvt_bf16<<<2048, 256, 0, stream>>>(x,   xb, (4*2048*1024)/4, 1.0f);
  cvt_bf16<<<2048, 256, 0, stream>>>(ctx, cb, (4*2048*1024)/4, 1.0f);
  cvt_w4<<<1024, 256, 0, stream>>>(Wq, Wk, Wv, Wo, wqb, wkb, wvb, wob, SCALE_LOG2E);

  gemm_bt<true, false><<<dim3(1024/128, 8192/128), 256, 0, stream>>>(xb, wqb, Qb, nullptr, 8192, 1024, 1024);
  gemm_bt<true, false><<<dim3(1024/128, 8192/128), 256, 0, stream>>>(cb, wkb, Kb, nullptr, 8192, 1024, 1024);
  gemm_bt<true, false><<<dim3(8192/128, 1024/128), 256, 0, stream>>>(wvb, cb, Vtb, nullptr, 1024, 8192, 1024);

  flash_attn<<<dim3(2048/128, 16, 4), 256, 0, stream>>>(Qb, Kb, Vtb, Ob);

  gemm_bt<false, true><<<dim3(1024/128, 8192/128), 256, 0, stream>>>(Ob, wob, out, bo, 8192, 1024, 1024);
}

// Round 7
// 339.485 us; speedup vs baseline: 1.6731x; 1.0462x over previous
//
#include <hip/hip_runtime.h>
#include <cstdint>
#include <cstddef>

// ---------------------------------------------------------------------------
// CrossAttention: out = softmax((x Wq^T)(ctx Wk^T)^T * scale) (ctx Wv^T) Wo^T + bo
// B=4, NQ=NK=2048, QDIM=CDIM=1024, H=16, DH=64, inner=1024.
// SCALE*log2(e) folded into Wq; softmax in exp2 domain.
// bf16 MFMA (16x16x32), fp32 accumulation, swapped-QK flash attention.
// R6: Q/K/Vt projections merged into ONE 1536-block dispatch (gemm3) so the
// 2-phase GEMM structure gets 5-6 resident blocks/CU (TLP hides the
// vmcnt(0)+barrier drain; m102 curve: 2 blk/CU = 320 TF, 4+ = 830 TF).
// ---------------------------------------------------------------------------

typedef __attribute__((ext_vector_type(8))) short short8;
typedef __attribute__((ext_vector_type(4))) float f32x4;
typedef __attribute__((ext_vector_type(4))) unsigned short ushort4v;

#define GLD16(gsrc, ldst) \
  __builtin_amdgcn_global_load_lds((const __attribute__((address_space(1))) unsigned int*)(gsrc), \
                                   (__attribute__((address_space(3))) unsigned int*)(ldst), 16, 0, 0)

__device__ __forceinline__ unsigned short f32_to_bf16(float f) {
  unsigned int u = __builtin_bit_cast(unsigned int, f);
  u += 0x7FFFu + ((u >> 16) & 1u);   // RNE
  return (unsigned short)(u >> 16);
}

// T12: packed f32x2 -> bf16x2, single VALU op (no builtin on gfx950; asm per guide)
__device__ __forceinline__ unsigned int cvtpk_bf16(float lo, float hi) {
  unsigned int r;
  asm("v_cvt_pk_bf16_f32 %0, %1, %2" : "=v"(r) : "v"(lo), "v"(hi));
  return r;
}

__device__ __forceinline__ float exp2_fast(float x) {
#if __has_builtin(__builtin_amdgcn_exp2f)
  return __builtin_amdgcn_exp2f(x);
#else
  return exp2f(x);
#endif
}

// ---------------- fp32 -> bf16 conversions ----------------------------------
// x and ctx (8.4M elems each) in one 4096-block launch.
__global__ __launch_bounds__(256) void cvt_x2(const float* __restrict__ x,
                                              const float* __restrict__ ctx,
                                              unsigned short* __restrict__ xb,
                                              unsigned short* __restrict__ cb) {
  const int seg = blockIdx.x >> 11;
  const float* in = seg ? ctx : x;
  unsigned short* out = seg ? cb : xb;
  int i = (blockIdx.x & 2047) * 256 + threadIdx.x;
  const int stride = 2048 * 256;
#pragma unroll
  for (int k = 0; k < 4; ++k, i += stride) {
    float4 v = reinterpret_cast<const float4*>(in)[i];
    ushort4v o;
    o.x = f32_to_bf16(v.x);
    o.y = f32_to_bf16(v.y);
    o.z = f32_to_bf16(v.z);
    o.w = f32_to_bf16(v.w);
    reinterpret_cast<ushort4v*>(out)[i] = o;
  }
}

// 4 weight matrices (1024x1024 each) in one launch; scale applied to w0 only.
__global__ __launch_bounds__(256) void cvt_w4(const float* __restrict__ a, const float* __restrict__ b,
                                              const float* __restrict__ c, const float* __restrict__ d,
                                              unsigned short* __restrict__ oa, unsigned short* __restrict__ ob,
                                              unsigned short* __restrict__ oc, unsigned short* __restrict__ od,
                                              float scale_a) {
  int seg = blockIdx.x >> 8;          // 0..3
  int blk = blockIdx.x & 255;
  const float* in = seg == 0 ? a : seg == 1 ? b : seg == 2 ? c : d;
  unsigned short* out = seg == 0 ? oa : seg == 1 ? ob : seg == 2 ? oc : od;
  float sc = seg == 0 ? scale_a : 1.0f;
  int i = blk * 256 + threadIdx.x;
#pragma unroll
  for (int k = 0; k < 4; ++k, i += 65536) {
    float4 v = reinterpret_cast<const float4*>(in)[i];
    ushort4v o;
    o.x = f32_to_bf16(v.x * sc);
    o.y = f32_to_bf16(v.y * sc);
    o.z = f32_to_bf16(v.z * sc);
    o.w = f32_to_bf16(v.w * sc);
    reinterpret_cast<ushort4v*>(out)[i] = o;
  }
}

// ---------------- GEMM core: C[M,N] = A[M,K] * B[N,K]^T ---------------------
// 128x128 tile, BK=32, double-buffered LDS, single-barrier 2-phase pipeline.
// smA/smB: 2 x 128x32 bf16 each (8192 bytes per buffer).
template<bool BF16_OUT, bool BIAS>
__device__ __forceinline__ void gemm_core(const unsigned short* __restrict__ A,
                                          const unsigned short* __restrict__ Bm,
                                          void* __restrict__ Cout,
                                          const float* __restrict__ bias,
                                          int M, int N, int K, int bx, int by,
                                          unsigned short* smA, unsigned short* smB) {
  const int t    = threadIdx.x;
  const int lane = t & 63;
  const int wid  = t >> 6;
  const int l15  = lane & 15;
  const int l16  = lane >> 4;
  const int m0   = by * 128;
  const int n0   = bx * 128;
  const int wr   = (wid >> 1) * 64;
  const int wc   = (wid & 1) * 64;

  f32x4 acc[4][4];
#pragma unroll
  for (int i = 0; i < 4; ++i)
#pragma unroll
    for (int j = 0; j < 4; ++j) acc[i][j] = (f32x4){0.f, 0.f, 0.f, 0.f};

  const char* Abase = (const char*)A + (size_t)m0 * K * 2;
  const char* Bbase = (const char*)Bm + (size_t)n0 * K * 2;

  auto stageG = [&](int bufi, int k0) {
#pragma unroll
    for (int i = 0; i < 2; ++i) {
      int g = i * 256 + t;
      int r = g >> 2, c = g & 3;
      int cs = c ^ ((r >> 1) & 3);  // bank swizzle
      GLD16(Abase + (size_t)r * (K * 2) + (size_t)k0 * 2 + cs * 16,
            (char*)smA + bufi * 8192 + (g & ~63) * 16);
      GLD16(Bbase + (size_t)r * (K * 2) + (size_t)k0 * 2 + cs * 16,
            (char*)smB + bufi * 8192 + (g & ~63) * 16);
    }
  };

  const int nk = K >> 5;
  stageG(0, 0);
  asm volatile("s_waitcnt vmcnt(0)" ::: "memory");
  __builtin_amdgcn_s_barrier();

  for (int t0 = 0; t0 < nk; ++t0) {
    const int bufi = t0 & 1;
    if (t0 + 1 < nk) stageG(bufi ^ 1, (t0 + 1) * 32);

    short8 af[4], bfv[4];
#pragma unroll
    for (int mi = 0; mi < 4; ++mi) {
      int row = wr + mi * 16 + l15;
      int cs = l16 ^ ((row >> 1) & 3);
      af[mi] = *reinterpret_cast<const short8*>((const char*)smA + bufi * 8192 + row * 64 + cs * 16);
    }
#pragma unroll
    for (int ni = 0; ni < 4; ++ni) {
      int row = wc + ni * 16 + l15;
      int cs = l16 ^ ((row >> 1) & 3);
      bfv[ni] = *reinterpret_cast<const short8*>((const char*)smB + bufi * 8192 + row * 64 + cs * 16);
    }
    __builtin_amdgcn_s_setprio(1);
#pragma unroll
    for (int mi = 0; mi < 4; ++mi)
#pragma unroll
      for (int ni = 0; ni < 4; ++ni)
        acc[mi][ni] = __builtin_amdgcn_mfma_f32_16x16x32_bf16(af[mi], bfv[ni], acc[mi][ni], 0, 0, 0);
    __builtin_amdgcn_s_setprio(0);

    asm volatile("s_waitcnt vmcnt(0)" ::: "memory");  // next-tile loads landed
    __builtin_amdgcn_s_barrier();
  }

  // epilogue: C/D layout col=lane&15, row=(lane>>4)*4+r
#pragma unroll
  for (int mi = 0; mi < 4; ++mi)
#pragma unroll
    for (int ni = 0; ni < 4; ++ni)
#pragma unroll
      for (int r = 0; r < 4; ++r) {
        int row = m0 + wr + mi * 16 + l16 * 4 + r;
        int col = n0 + wc + ni * 16 + l15;
        float v = acc[mi][ni][r];
        if (BIAS) v += bias[col];
        if (BF16_OUT)
          ((unsigned short*)Cout)[(size_t)row * N + col] = f32_to_bf16(v);
        else
          ((float*)Cout)[(size_t)row * N + col] = v;
      }
}

// Standalone GEMM (used for the output projection).
template<bool BF16_OUT, bool BIAS>
__global__ __launch_bounds__(256) void gemm_bt(const unsigned short* __restrict__ A,
                                               const unsigned short* __restrict__ Bm,
                                               void* __restrict__ Cout,
                                               const float* __restrict__ bias,
                                               int M, int N, int K) {
  __shared__ __align__(16) unsigned short smA[2 * 128 * 32];
  __shared__ __align__(16) unsigned short smB[2 * 128 * 32];
  gemm_core<BF16_OUT, BIAS>(A, Bm, Cout, bias, M, N, K, blockIdx.x, blockIdx.y, smA, smB);
}

// Fused Q-proj + K-proj + Vt in one 1536-block dispatch (per-block work equal).
__global__ __launch_bounds__(256) void gemm3(const unsigned short* __restrict__ xb,
                                             const unsigned short* __restrict__ cb,
                                             const unsigned short* __restrict__ wqb,
                                             const unsigned short* __restrict__ wkb,
                                             const unsigned short* __restrict__ wvb,
                                             unsigned short* __restrict__ Qb,
                                             unsigned short* __restrict__ Kb,
                                             unsigned short* __restrict__ Vtb) {
  __shared__ __align__(16) unsigned short smA[2 * 128 * 32];
  __shared__ __align__(16) unsigned short smB[2 * 128 * 32];
  const int id = blockIdx.x;
  if (id < 512) {         // Q = xb * Wq^T : M=8192 N=1024 (grid 8 x 64)
    gemm_core<true, false>(xb, wqb, Qb, nullptr, 8192, 1024, 1024, id & 7, id >> 3, smA, smB);
  } else if (id < 1024) { // K = cb * Wk^T : M=8192 N=1024
    int l = id - 512;
    gemm_core<true, false>(cb, wkb, Kb, nullptr, 8192, 1024, 1024, l & 7, l >> 3, smA, smB);
  } else {                // Vt = Wv * cb^T : M=1024 N=8192 (grid 64 x 8)
    int l = id - 1024;
    gemm_core<true, false>(wvb, cb, Vtb, nullptr, 1024, 8192, 1024, l & 63, l >> 6, smA, smB);
  }
}

// ---------------- Flash attention v3 (unchanged, validated) -----------------
// Swapped QK^T (S^T = mfma(A=K, B=Q)): C col=l15=q, row=l16*4+r=k.
// exp2-domain softmax (log2e folded into Wq). P pack via v_cvt_pk_bf16_f32.
// Single-barrier 2-phase pipeline: stage(next) overlaps full tile compute.
__global__ __launch_bounds__(256, 3) void flash_attn(const unsigned short* __restrict__ Q,
                                                     const unsigned short* __restrict__ Kb,
                                                     const unsigned short* __restrict__ Vt,
                                                     unsigned short* __restrict__ O) {
  __shared__ __align__(16) unsigned short smK[2][64 * 64];
  __shared__ __align__(16) unsigned short smV[2][64 * 64];
  __shared__ __align__(16) unsigned int   smP[4][32 * 36];  // per-wave P, padded

  const int t    = threadIdx.x;
  const int lane = t & 63;
  const int wid  = t >> 6;
  const int l15  = lane & 15;
  const int l16  = lane >> 4;
  const int qt   = blockIdx.x;
  const int h    = blockIdx.y;
  const int b    = blockIdx.z;

  const char* Kbase = (const char*)Kb + ((size_t)(b * 2048) * 1024 + h * 64) * 2;
  const char* Vbase = (const char*)Vt + ((size_t)(h * 64) * 8192 + b * 2048) * 2;
  unsigned int* smPw = &smP[wid][0];

  auto stage = [&](int buf, int j0) {
#pragma unroll
    for (int i = 0; i < 2; ++i) {
      int g = i * 256 + t;
      int r = g >> 3, c = g & 7;
      int cs = c ^ (r & 7);
      const char* srcK = Kbase + (size_t)(j0 + r) * 2048 + cs * 16;
      const char* srcV = Vbase + (size_t)r * 16384 + (size_t)j0 * 2 + cs * 16;
      GLD16(srcK, (char*)&smK[buf][0] + (g & ~63) * 16);
      GLD16(srcV, (char*)&smV[buf][0] + (g & ~63) * 16);
    }
  };

  stage(0, 0);

  // Q as B-operand: col(q)=l15, d-elems = kk*32 + l16*8 + j
  short8 qf[2][2];
#pragma unroll
  for (int qg = 0; qg < 2; ++qg)
#pragma unroll
    for (int kk = 0; kk < 2; ++kk) {
      size_t idx = (size_t)(b * 2048 + qt * 128 + wid * 32 + qg * 16 + l15) * 1024
                 + (size_t)h * 64 + kk * 32 + l16 * 8;
      qf[qg][kk] = *reinterpret_cast<const short8*>(&Q[idx]);
    }

  f32x4 accO[2][4];
  float m_run[2], l_run[2];
#pragma unroll
  for (int qg = 0; qg < 2; ++qg) {
    m_run[qg] = -1.0e30f;
    l_run[qg] = 0.f;
#pragma unroll
    for (int di = 0; di < 4; ++di) accO[qg][di] = (f32x4){0.f, 0.f, 0.f, 0.f};
  }

  asm volatile("s_waitcnt vmcnt(0)" ::: "memory");
  __builtin_amdgcn_s_barrier();

  for (int jt = 0; jt < 32; ++jt) {
    const int buf = jt & 1;
    if (jt < 31) stage(buf ^ 1, (jt + 1) * 64);  // overlaps entire tile compute

    // ---- QK^T (swapped): s[qg][kc], col=q, row=k ----
    short8 kf[4][2];
#pragma unroll
    for (int kc = 0; kc < 4; ++kc)
#pragma unroll
      for (int kk = 0; kk < 2; ++kk) {
        int row = kc * 16 + l15;
        int cs = (kk * 4 + l16) ^ (row & 7);
        kf[kc][kk] = *reinterpret_cast<const short8*>((const char*)&smK[buf][0] + row * 128 + cs * 16);
      }
    f32x4 s[2][4];
    const f32x4 z = (f32x4){0.f, 0.f, 0.f, 0.f};
    __builtin_amdgcn_s_setprio(1);
#pragma unroll
    for (int qg = 0; qg < 2; ++qg)
#pragma unroll
      for (int kc = 0; kc < 4; ++kc) {
        f32x4 tmp = __builtin_amdgcn_mfma_f32_16x16x32_bf16(kf[kc][0], qf[qg][0], z, 0, 0, 0);
        s[qg][kc] = __builtin_amdgcn_mfma_f32_16x16x32_bf16(kf[kc][1], qf[qg][1], tmp, 0, 0, 0);
      }
    __builtin_amdgcn_s_setprio(0);

    // ---- V fragments (DS issues under softmax VALU) ----
    short8 vf[4][2];
#pragma unroll
    for (int di = 0; di < 4; ++di)
#pragma unroll
      for (int kk = 0; kk < 2; ++kk) {
        int row = di * 16 + l15;
        int cs = (kk * 4 + l16) ^ (row & 7);
        vf[di][kk] = *reinterpret_cast<const short8*>((const char*)&smV[buf][0] + row * 128 + cs * 16);
      }

    // ---- online softmax, exp2 domain (lane owns q = qg*16+l15) ----
#pragma unroll
    for (int qg = 0; qg < 2; ++qg) {
      float vmax = s[qg][0][0];
#pragma unroll
      for (int kc = 0; kc < 4; ++kc)
#pragma unroll
        for (int r = 0; r < 4; ++r) vmax = fmaxf(vmax, s[qg][kc][r]);
      vmax = fmaxf(vmax, __shfl_xor(vmax, 16));
      vmax = fmaxf(vmax, __shfl_xor(vmax, 32));

      if (__any(vmax > m_run[qg] + 11.5f)) {   // T13 defer-max (2^11.5 ~ e^8)
        float mnew = fmaxf(m_run[qg], vmax);
        float alpha = exp2_fast(m_run[qg] - mnew);
        m_run[qg] = mnew;
        l_run[qg] *= alpha;
        int av = __builtin_bit_cast(int, alpha);
#pragma unroll
        for (int r = 0; r < 4; ++r) {
          float at = __builtin_bit_cast(float, __builtin_amdgcn_ds_bpermute((l16 * 4 + r) * 4, av));
#pragma unroll
          for (int di = 0; di < 4; ++di) accO[qg][di][r] *= at;
        }
      }

      float rsum = 0.f;
#pragma unroll
      for (int kc = 0; kc < 4; ++kc)
#pragma unroll
        for (int r = 0; r < 4; ++r) {
          float p = exp2_fast(s[qg][kc][r] - m_run[qg]);
          s[qg][kc][r] = p;
          rsum += p;
        }
      rsum += __shfl_xor(rsum, 16);
      rsum += __shfl_xor(rsum, 32);
      l_run[qg] += rsum;

      // pack pairs (k, k+1) via cvt_pk and write to wave-private P-LDS
#pragma unroll
      for (int kc = 0; kc < 4; ++kc) {
        unsigned int w0 = cvtpk_bf16(s[qg][kc][0], s[qg][kc][1]);
        unsigned int w1 = cvtpk_bf16(s[qg][kc][2], s[qg][kc][3]);
        int word = (qg * 16 + l15) * 36 + kc * 8 + l16 * 2;
        *reinterpret_cast<uint2*>(&smPw[word]) = uint2{w0, w1};
      }
    }

    // same-wave DS ordering: P writes landed before A-frag reads
    asm volatile("s_waitcnt lgkmcnt(0)" ::: "memory");
    __builtin_amdgcn_sched_barrier(0);

    short8 pf[2][2];
#pragma unroll
    for (int qg = 0; qg < 2; ++qg)
#pragma unroll
      for (int kk = 0; kk < 2; ++kk) {
        int word = (qg * 16 + l15) * 36 + kk * 16 + l16 * 4;
        pf[qg][kk] = *reinterpret_cast<const short8*>(&smPw[word]);
      }

    __builtin_amdgcn_s_setprio(1);
#pragma unroll
    for (int qg = 0; qg < 2; ++qg)
#pragma unroll
      for (int di = 0; di < 4; ++di) {
        accO[qg][di] = __builtin_amdgcn_mfma_f32_16x16x32_bf16(pf[qg][0], vf[di][0], accO[qg][di], 0, 0, 0);
        accO[qg][di] = __builtin_amdgcn_mfma_f32_16x16x32_bf16(pf[qg][1], vf[di][1], accO[qg][di], 0, 0, 0);
      }
    __builtin_amdgcn_s_setprio(0);

    asm volatile("s_waitcnt vmcnt(0)" ::: "memory");  // next-tile stage landed
    __builtin_amdgcn_s_barrier();
  }

  // ---- epilogue: normalize (transpose 1/l to accO rows) and store ----
#pragma unroll
  for (int qg = 0; qg < 2; ++qg) {
    float inv = 1.f / l_run[qg];
    int iv = __builtin_bit_cast(int, inv);
#pragma unroll
    for (int r = 0; r < 4; ++r) {
      float it = __builtin_bit_cast(float, __builtin_amdgcn_ds_bpermute((l16 * 4 + r) * 4, iv));
      int row = b * 2048 + qt * 128 + wid * 32 + qg * 16 + l16 * 4 + r;
#pragma unroll
      for (int di = 0; di < 4; ++di) {
        int col = h * 64 + di * 16 + l15;
        O[(size_t)row * 1024 + col] = f32_to_bf16(accO[qg][di][r] * it);
      }
    }
  }
}

// ---------------------------------------------------------------------------
extern "C" void kernel_launch(void* const* d_in, const int* in_sizes, int n_in,
                              void* d_out, int out_size, void* d_ws, size_t ws_size,
                              hipStream_t stream) {
  (void)in_sizes; (void)n_in; (void)out_size; (void)ws_size;
  const float* x   = (const float*)d_in[0];
  const float* ctx = (const float*)d_in[1];
  const float* Wq  = (const float*)d_in[2];
  const float* Wk  = (const float*)d_in[3];
  const float* Wv  = (const float*)d_in[4];
  const float* Wo  = (const float*)d_in[5];
  const float* bo  = (const float*)d_in[6];
  float* out = (float*)d_out;

  char* ws = (char*)d_ws;
  const size_t MB = 1024 * 1024;
  unsigned short* xb  = (unsigned short*)(ws + 0);
  unsigned short* cb  = (unsigned short*)(ws + 16 * MB);
  unsigned short* Qb  = (unsigned short*)(ws + 32 * MB);
  unsigned short* Kb  = (unsigned short*)(ws + 48 * MB);
  unsigned short* Vtb = (unsigned short*)(ws + 64 * MB);
  unsigned short* wqb = (unsigned short*)(ws + 80 * MB);
  unsigned short* wkb = (unsigned short*)(ws + 82 * MB);
  unsigned short* wvb = (unsigned short*)(ws + 84 * MB);
  unsigned short* wob = (unsigned short*)(ws + 86 * MB);
  unsigned short* Ob  = xb;  // alias: xb dead after Q projection

  const float SCALE_LOG2E = 0.125f * 1.4426950408889634f;  // DH^-0.5 * log2(e)

  cvt_x2<<<4096, 256, 0, stream>>>(x, ctx, xb, cb);
  cvt_w4<<<1024, 256, 0, stream>>>(Wq, Wk, Wv, Wo, wqb, wkb, wvb, wob, SCALE_LOG2E);

  // Q-proj + K-proj + Vt in one dispatch (1536 blocks -> 5-6 blocks/CU TLP)
  gemm3<<<1536, 256, 0, stream>>>(xb, cb, wqb, wkb, wvb, Qb, Kb, Vtb);

  flash_attn<<<dim3(2048/128, 16, 4), 256, 0, stream>>>(Qb, Kb, Vtb, Ob);

  gemm_bt<false, true><<<dim3(1024/128, 8192/128), 256, 0, stream>>>(Ob, wob, out, bo, 8192, 1024, 1024);
}

// Round 8
// 339.251 us; speedup vs baseline: 1.6743x; 1.0007x over previous
//
#include <hip/hip_runtime.h>
#include <cstdint>
#include <cstddef>

// ---------------------------------------------------------------------------
// CrossAttention: out = softmax((x Wq^T)(ctx Wk^T)^T * scale) (ctx Wv^T) Wo^T + bo
// B=4, NQ=NK=2048, QDIM=CDIM=1024, H=16, DH=64, inner=1024.
// SCALE*log2(e) folded into Wq; softmax in exp2 domain.
// bf16 MFMA (16x16x32), fp32 accumulation, swapped-QK flash attention.
// R7: GEMM core -> triple-buffered LDS, counted vmcnt(4) (never drains in
// main loop; loads span 2 compute phases), ONE barrier per K-step.
// XCD-aware block swizzle on both GEMM dispatches (T1, bijective: nwg%8==0).
// ---------------------------------------------------------------------------

typedef __attribute__((ext_vector_type(8))) short short8;
typedef __attribute__((ext_vector_type(4))) float f32x4;
typedef __attribute__((ext_vector_type(4))) unsigned short ushort4v;

#define GLD16(gsrc, ldst) \
  __builtin_amdgcn_global_load_lds((const __attribute__((address_space(1))) unsigned int*)(gsrc), \
                                   (__attribute__((address_space(3))) unsigned int*)(ldst), 16, 0, 0)

__device__ __forceinline__ unsigned short f32_to_bf16(float f) {
  unsigned int u = __builtin_bit_cast(unsigned int, f);
  u += 0x7FFFu + ((u >> 16) & 1u);   // RNE
  return (unsigned short)(u >> 16);
}

// T12: packed f32x2 -> bf16x2, single VALU op (no builtin on gfx950; asm per guide)
__device__ __forceinline__ unsigned int cvtpk_bf16(float lo, float hi) {
  unsigned int r;
  asm("v_cvt_pk_bf16_f32 %0, %1, %2" : "=v"(r) : "v"(lo), "v"(hi));
  return r;
}

__device__ __forceinline__ float exp2_fast(float x) {
#if __has_builtin(__builtin_amdgcn_exp2f)
  return __builtin_amdgcn_exp2f(x);
#else
  return exp2f(x);
#endif
}

// ---------------- fp32 -> bf16 conversions ----------------------------------
__global__ __launch_bounds__(256) void cvt_x2(const float* __restrict__ x,
                                              const float* __restrict__ ctx,
                                              unsigned short* __restrict__ xb,
                                              unsigned short* __restrict__ cb) {
  const int seg = blockIdx.x >> 11;
  const float* in = seg ? ctx : x;
  unsigned short* out = seg ? cb : xb;
  int i = (blockIdx.x & 2047) * 256 + threadIdx.x;
  const int stride = 2048 * 256;
#pragma unroll
  for (int k = 0; k < 4; ++k, i += stride) {
    float4 v = reinterpret_cast<const float4*>(in)[i];
    ushort4v o;
    o.x = f32_to_bf16(v.x);
    o.y = f32_to_bf16(v.y);
    o.z = f32_to_bf16(v.z);
    o.w = f32_to_bf16(v.w);
    reinterpret_cast<ushort4v*>(out)[i] = o;
  }
}

__global__ __launch_bounds__(256) void cvt_w4(const float* __restrict__ a, const float* __restrict__ b,
                                              const float* __restrict__ c, const float* __restrict__ d,
                                              unsigned short* __restrict__ oa, unsigned short* __restrict__ ob,
                                              unsigned short* __restrict__ oc, unsigned short* __restrict__ od,
                                              float scale_a) {
  int seg = blockIdx.x >> 8;          // 0..3
  int blk = blockIdx.x & 255;
  const float* in = seg == 0 ? a : seg == 1 ? b : seg == 2 ? c : d;
  unsigned short* out = seg == 0 ? oa : seg == 1 ? ob : seg == 2 ? oc : od;
  float sc = seg == 0 ? scale_a : 1.0f;
  int i = blk * 256 + threadIdx.x;
#pragma unroll
  for (int k = 0; k < 4; ++k, i += 65536) {
    float4 v = reinterpret_cast<const float4*>(in)[i];
    ushort4v o;
    o.x = f32_to_bf16(v.x * sc);
    o.y = f32_to_bf16(v.y * sc);
    o.z = f32_to_bf16(v.z * sc);
    o.w = f32_to_bf16(v.w * sc);
    reinterpret_cast<ushort4v*>(out)[i] = o;
  }
}

// ---------------- GEMM core: C[M,N] = A[M,K] * B[N,K]^T ---------------------
// 128x128 tile, BK=32, TRIPLE-buffered LDS (3 x 8 KB per operand), counted
// vmcnt(4): tile t's loads awaited 2 iters after issue; 1 barrier per step.
template<bool BF16_OUT, bool BIAS>
__device__ __forceinline__ void gemm_core(const unsigned short* __restrict__ A,
                                          const unsigned short* __restrict__ Bm,
                                          void* __restrict__ Cout,
                                          const float* __restrict__ bias,
                                          int M, int N, int K, int bx, int by,
                                          unsigned short* smA, unsigned short* smB) {
  const int t    = threadIdx.x;
  const int lane = t & 63;
  const int wid  = t >> 6;
  const int l15  = lane & 15;
  const int l16  = lane >> 4;
  const int m0   = by * 128;
  const int n0   = bx * 128;
  const int wr   = (wid >> 1) * 64;
  const int wc   = (wid & 1) * 64;

  f32x4 acc[4][4];
#pragma unroll
  for (int i = 0; i < 4; ++i)
#pragma unroll
    for (int j = 0; j < 4; ++j) acc[i][j] = (f32x4){0.f, 0.f, 0.f, 0.f};

  const char* Abase = (const char*)A + (size_t)m0 * K * 2;
  const char* Bbase = (const char*)Bm + (size_t)n0 * K * 2;

  auto stageG = [&](int bufi, int k0) {
#pragma unroll
    for (int i = 0; i < 2; ++i) {
      int g = i * 256 + t;
      int r = g >> 2, c = g & 3;
      int cs = c ^ ((r >> 1) & 3);  // bank swizzle
      GLD16(Abase + (size_t)r * (K * 2) + (size_t)k0 * 2 + cs * 16,
            (char*)smA + bufi * 8192 + (g & ~63) * 16);
      GLD16(Bbase + (size_t)r * (K * 2) + (size_t)k0 * 2 + cs * 16,
            (char*)smB + bufi * 8192 + (g & ~63) * 16);
    }
  };

  const int nk = K >> 5;   // >= 2 for all our shapes (K=1024)
  stageG(0, 0);
  stageG(1, 32);           // 8 GLDs/thread in flight

  for (int t0 = 0; t0 < nk; ++t0) {
    const int bufi = t0 % 3;
    // wait tile t0's 4 loads (issued 2 iters ago); keep t0+1's 4 in flight
    if (t0 < nk - 1) { asm volatile("s_waitcnt vmcnt(4)" ::: "memory"); }
    else             { asm volatile("s_waitcnt vmcnt(0)" ::: "memory"); }
    __builtin_amdgcn_s_barrier();   // all waves' t0-loads visible; all reads of
                                    // buf[(t0+2)%3] (iter t0-1) complete
    if (t0 + 2 < nk) {
      int bn = bufi + 2; if (bn >= 3) bn -= 3;
      stageG(bn, (t0 + 2) * 32);
    }

    short8 af[4], bfv[4];
#pragma unroll
    for (int mi = 0; mi < 4; ++mi) {
      int row = wr + mi * 16 + l15;
      int cs = l16 ^ ((row >> 1) & 3);
      af[mi] = *reinterpret_cast<const short8*>((const char*)smA + bufi * 8192 + row * 64 + cs * 16);
    }
#pragma unroll
    for (int ni = 0; ni < 4; ++ni) {
      int row = wc + ni * 16 + l15;
      int cs = l16 ^ ((row >> 1) & 3);
      bfv[ni] = *reinterpret_cast<const short8*>((const char*)smB + bufi * 8192 + row * 64 + cs * 16);
    }
    __builtin_amdgcn_s_setprio(1);
#pragma unroll
    for (int mi = 0; mi < 4; ++mi)
#pragma unroll
      for (int ni = 0; ni < 4; ++ni)
        acc[mi][ni] = __builtin_amdgcn_mfma_f32_16x16x32_bf16(af[mi], bfv[ni], acc[mi][ni], 0, 0, 0);
    __builtin_amdgcn_s_setprio(0);
  }

  // epilogue: C/D layout col=lane&15, row=(lane>>4)*4+r
#pragma unroll
  for (int mi = 0; mi < 4; ++mi)
#pragma unroll
    for (int ni = 0; ni < 4; ++ni)
#pragma unroll
      for (int r = 0; r < 4; ++r) {
        int row = m0 + wr + mi * 16 + l16 * 4 + r;
        int col = n0 + wc + ni * 16 + l15;
        float v = acc[mi][ni][r];
        if (BIAS) v += bias[col];
        if (BF16_OUT)
          ((unsigned short*)Cout)[(size_t)row * N + col] = f32_to_bf16(v);
        else
          ((float*)Cout)[(size_t)row * N + col] = v;
      }
}

// Output projection: 1D launch, XCD-swizzled (nwg=512, 512%8==0 -> bijective).
__global__ __launch_bounds__(256) void gemm_o(const unsigned short* __restrict__ Ob,
                                              const unsigned short* __restrict__ wob,
                                              float* __restrict__ out,
                                              const float* __restrict__ bo) {
  __shared__ __align__(16) unsigned short smA[3 * 128 * 32];
  __shared__ __align__(16) unsigned short smB[3 * 128 * 32];
  const int orig = blockIdx.x;
  const int wgid = (orig & 7) * 64 + (orig >> 3);   // 512 blocks / 8 XCDs
  gemm_core<false, true>(Ob, wob, out, bo, 8192, 1024, 1024, wgid & 7, wgid >> 3, smA, smB);
}

// Fused Q-proj + K-proj + Vt, one 1536-block dispatch, XCD-swizzled.
__global__ __launch_bounds__(256) void gemm3(const unsigned short* __restrict__ xb,
                                             const unsigned short* __restrict__ cb,
                                             const unsigned short* __restrict__ wqb,
                                             const unsigned short* __restrict__ wkb,
                                             const unsigned short* __restrict__ wvb,
                                             unsigned short* __restrict__ Qb,
                                             unsigned short* __restrict__ Kb,
                                             unsigned short* __restrict__ Vtb) {
  __shared__ __align__(16) unsigned short smA[3 * 128 * 32];
  __shared__ __align__(16) unsigned short smB[3 * 128 * 32];
  const int orig = blockIdx.x;
  const int id = (orig & 7) * 192 + (orig >> 3);    // 1536 blocks / 8 XCDs
  if (id < 512) {         // Q = xb * Wq^T : M=8192 N=1024 (grid 8 x 64)
    gemm_core<true, false>(xb, wqb, Qb, nullptr, 8192, 1024, 1024, id & 7, id >> 3, smA, smB);
  } else if (id < 1024) { // K = cb * Wk^T : M=8192 N=1024
    int l = id - 512;
    gemm_core<true, false>(cb, wkb, Kb, nullptr, 8192, 1024, 1024, l & 7, l >> 3, smA, smB);
  } else {                // Vt = Wv * cb^T : M=1024 N=8192 (grid 64 x 8)
    int l = id - 1024;
    gemm_core<true, false>(wvb, cb, Vtb, nullptr, 1024, 8192, 1024, l & 63, l >> 6, smA, smB);
  }
}

// ---------------- Flash attention v3 (unchanged, validated) -----------------
__global__ __launch_bounds__(256, 3) void flash_attn(const unsigned short* __restrict__ Q,
                                                     const unsigned short* __restrict__ Kb,
                                                     const unsigned short* __restrict__ Vt,
                                                     unsigned short* __restrict__ O) {
  __shared__ __align__(16) unsigned short smK[2][64 * 64];
  __shared__ __align__(16) unsigned short smV[2][64 * 64];
  __shared__ __align__(16) unsigned int   smP[4][32 * 36];  // per-wave P, padded

  const int t    = threadIdx.x;
  const int lane = t & 63;
  const int wid  = t >> 6;
  const int l15  = lane & 15;
  const int l16  = lane >> 4;
  const int qt   = blockIdx.x;
  const int h    = blockIdx.y;
  const int b    = blockIdx.z;

  const char* Kbase = (const char*)Kb + ((size_t)(b * 2048) * 1024 + h * 64) * 2;
  const char* Vbase = (const char*)Vt + ((size_t)(h * 64) * 8192 + b * 2048) * 2;
  unsigned int* smPw = &smP[wid][0];

  auto stage = [&](int buf, int j0) {
#pragma unroll
    for (int i = 0; i < 2; ++i) {
      int g = i * 256 + t;
      int r = g >> 3, c = g & 7;
      int cs = c ^ (r & 7);
      const char* srcK = Kbase + (size_t)(j0 + r) * 2048 + cs * 16;
      const char* srcV = Vbase + (size_t)r * 16384 + (size_t)j0 * 2 + cs * 16;
      GLD16(srcK, (char*)&smK[buf][0] + (g & ~63) * 16);
      GLD16(srcV, (char*)&smV[buf][0] + (g & ~63) * 16);
    }
  };

  stage(0, 0);

  // Q as B-operand: col(q)=l15, d-elems = kk*32 + l16*8 + j
  short8 qf[2][2];
#pragma unroll
  for (int qg = 0; qg < 2; ++qg)
#pragma unroll
    for (int kk = 0; kk < 2; ++kk) {
      size_t idx = (size_t)(b * 2048 + qt * 128 + wid * 32 + qg * 16 + l15) * 1024
                 + (size_t)h * 64 + kk * 32 + l16 * 8;
      qf[qg][kk] = *reinterpret_cast<const short8*>(&Q[idx]);
    }

  f32x4 accO[2][4];
  float m_run[2], l_run[2];
#pragma unroll
  for (int qg = 0; qg < 2; ++qg) {
    m_run[qg] = -1.0e30f;
    l_run[qg] = 0.f;
#pragma unroll
    for (int di = 0; di < 4; ++di) accO[qg][di] = (f32x4){0.f, 0.f, 0.f, 0.f};
  }

  asm volatile("s_waitcnt vmcnt(0)" ::: "memory");
  __builtin_amdgcn_s_barrier();

  for (int jt = 0; jt < 32; ++jt) {
    const int buf = jt & 1;
    if (jt < 31) stage(buf ^ 1, (jt + 1) * 64);  // overlaps entire tile compute

    // ---- QK^T (swapped): s[qg][kc], col=q, row=k ----
    short8 kf[4][2];
#pragma unroll
    for (int kc = 0; kc < 4; ++kc)
#pragma unroll
      for (int kk = 0; kk < 2; ++kk) {
        int row = kc * 16 + l15;
        int cs = (kk * 4 + l16) ^ (row & 7);
        kf[kc][kk] = *reinterpret_cast<const short8*>((const char*)&smK[buf][0] + row * 128 + cs * 16);
      }
    f32x4 s[2][4];
    const f32x4 z = (f32x4){0.f, 0.f, 0.f, 0.f};
    __builtin_amdgcn_s_setprio(1);
#pragma unroll
    for (int qg = 0; qg < 2; ++qg)
#pragma unroll
      for (int kc = 0; kc < 4; ++kc) {
        f32x4 tmp = __builtin_amdgcn_mfma_f32_16x16x32_bf16(kf[kc][0], qf[qg][0], z, 0, 0, 0);
        s[qg][kc] = __builtin_amdgcn_mfma_f32_16x16x32_bf16(kf[kc][1], qf[qg][1], tmp, 0, 0, 0);
      }
    __builtin_amdgcn_s_setprio(0);

    // ---- V fragments (DS issues under softmax VALU) ----
    short8 vf[4][2];
#pragma unroll
    for (int di = 0; di < 4; ++di)
#pragma unroll
      for (int kk = 0; kk < 2; ++kk) {
        int row = di * 16 + l15;
        int cs = (kk * 4 + l16) ^ (row & 7);
        vf[di][kk] = *reinterpret_cast<const short8*>((const char*)&smV[buf][0] + row * 128 + cs * 16);
      }

    // ---- online softmax, exp2 domain (lane owns q = qg*16+l15) ----
#pragma unroll
    for (int qg = 0; qg < 2; ++qg) {
      float vmax = s[qg][0][0];
#pragma unroll
      for (int kc = 0; kc < 4; ++kc)
#pragma unroll
        for (int r = 0; r < 4; ++r) vmax = fmaxf(vmax, s[qg][kc][r]);
      vmax = fmaxf(vmax, __shfl_xor(vmax, 16));
      vmax = fmaxf(vmax, __shfl_xor(vmax, 32));

      if (__any(vmax > m_run[qg] + 11.5f)) {   // T13 defer-max (2^11.5 ~ e^8)
        float mnew = fmaxf(m_run[qg], vmax);
        float alpha = exp2_fast(m_run[qg] - mnew);
        m_run[qg] = mnew;
        l_run[qg] *= alpha;
        int av = __builtin_bit_cast(int, alpha);
#pragma unroll
        for (int r = 0; r < 4; ++r) {
          float at = __builtin_bit_cast(float, __builtin_amdgcn_ds_bpermute((l16 * 4 + r) * 4, av));
#pragma unroll
          for (int di = 0; di < 4; ++di) accO[qg][di][r] *= at;
        }
      }

      float rsum = 0.f;
#pragma unroll
      for (int kc = 0; kc < 4; ++kc)
#pragma unroll
        for (int r = 0; r < 4; ++r) {
          float p = exp2_fast(s[qg][kc][r] - m_run[qg]);
          s[qg][kc][r] = p;
          rsum += p;
        }
      rsum += __shfl_xor(rsum, 16);
      rsum += __shfl_xor(rsum, 32);
      l_run[qg] += rsum;

      // pack pairs (k, k+1) via cvt_pk and write to wave-private P-LDS
#pragma unroll
      for (int kc = 0; kc < 4; ++kc) {
        unsigned int w0 = cvtpk_bf16(s[qg][kc][0], s[qg][kc][1]);
        unsigned int w1 = cvtpk_bf16(s[qg][kc][2], s[qg][kc][3]);
        int word = (qg * 16 + l15) * 36 + kc * 8 + l16 * 2;
        *reinterpret_cast<uint2*>(&smPw[word]) = uint2{w0, w1};
      }
    }

    // same-wave DS ordering: P writes landed before A-frag reads
    asm volatile("s_waitcnt lgkmcnt(0)" ::: "memory");
    __builtin_amdgcn_sched_barrier(0);

    short8 pf[2][2];
#pragma unroll
    for (int qg = 0; qg < 2; ++qg)
#pragma unroll
      for (int kk = 0; kk < 2; ++kk) {
        int word = (qg * 16 + l15) * 36 + kk * 16 + l16 * 4;
        pf[qg][kk] = *reinterpret_cast<const short8*>(&smPw[word]);
      }

    __builtin_amdgcn_s_setprio(1);
#pragma unroll
    for (int qg = 0; qg < 2; ++qg)
#pragma unroll
      for (int di = 0; di < 4; ++di) {
        accO[qg][di] = __builtin_amdgcn_mfma_f32_16x16x32_bf16(pf[qg][0], vf[di][0], accO[qg][di], 0, 0, 0);
        accO[qg][di] = __builtin_amdgcn_mfma_f32_16x16x32_bf16(pf[qg][1], vf[di][1], accO[qg][di], 0, 0, 0);
      }
    __builtin_amdgcn_s_setprio(0);

    asm volatile("s_waitcnt vmcnt(0)" ::: "memory");  // next-tile stage landed
    __builtin_amdgcn_s_barrier();
  }

  // ---- epilogue: normalize (transpose 1/l to accO rows) and store ----
#pragma unroll
  for (int qg = 0; qg < 2; ++qg) {
    float inv = 1.f / l_run[qg];
    int iv = __builtin_bit_cast(int, inv);
#pragma unroll
    for (int r = 0; r < 4; ++r) {
      float it = __builtin_bit_cast(float, __builtin_amdgcn_ds_bpermute((l16 * 4 + r) * 4, iv));
      int row = b * 2048 + qt * 128 + wid * 32 + qg * 16 + l16 * 4 + r;
#pragma unroll
      for (int di = 0; di < 4; ++di) {
        int col = h * 64 + di * 16 + l15;
        O[(size_t)row * 1024 + col] = f32_to_bf16(accO[qg][di][r] * it);
      }
    }
  }
}

// ---------------------------------------------------------------------------
extern "C" void kernel_launch(void* const* d_in, const int* in_sizes, int n_in,
                              void* d_out, int out_size, void* d_ws, size_t ws_size,
                              hipStream_t stream) {
  (void)in_sizes; (void)n_in; (void)out_size; (void)ws_size;
  const float* x   = (const float*)d_in[0];
  const float* ctx = (const float*)d_in[1];
  const float* Wq  = (const float*)d_in[2];
  const float* Wk  = (const float*)d_in[3];
  const float* Wv  = (const float*)d_in[4];
  const float* Wo  = (const float*)d_in[5];
  const float* bo  = (const float*)d_in[6];
  float* out = (float*)d_out;

  char* ws = (char*)d_ws;
  const size_t MB = 1024 * 1024;
  unsigned short* xb  = (unsigned short*)(ws + 0);
  unsigned short* cb  = (unsigned short*)(ws + 16 * MB);
  unsigned short* Qb  = (unsigned short*)(ws + 32 * MB);
  unsigned short* Kb  = (unsigned short*)(ws + 48 * MB);
  unsigned short* Vtb = (unsigned short*)(ws + 64 * MB);
  unsigned short* wqb = (unsigned short*)(ws + 80 * MB);
  unsigned short* wkb = (unsigned short*)(ws + 82 * MB);
  unsigned short* wvb = (unsigned short*)(ws + 84 * MB);
  unsigned short* wob = (unsigned short*)(ws + 86 * MB);
  unsigned short* Ob  = xb;  // alias: xb dead after Q projection

  const float SCALE_LOG2E = 0.125f * 1.4426950408889634f;  // DH^-0.5 * log2(e)

  cvt_x2<<<4096, 256, 0, stream>>>(x, ctx, xb, cb);
  cvt_w4<<<1024, 256, 0, stream>>>(Wq, Wk, Wv, Wo, wqb, wkb, wvb, wob, SCALE_LOG2E);

  // Q-proj + K-proj + Vt in one dispatch (1536 blocks, XCD-swizzled)
  gemm3<<<1536, 256, 0, stream>>>(xb, cb, wqb, wkb, wvb, Qb, Kb, Vtb);

  flash_attn<<<dim3(2048/128, 16, 4), 256, 0, stream>>>(Qb, Kb, Vtb, Ob);

  gemm_o<<<512, 256, 0, stream>>>(Ob, wob, out, bo);
}